// Round 1
// baseline (10232.325 us; speedup 1.0000x reference)
//
#include <hip/hip_runtime.h>
#include <hip/hip_bf16.h>
#include <cstddef>

// Problem constants
#define S_TOT 3072
#define HID_  1152
#define MLP_  4304
#define NH_   16
#define HD_   72
#define SEGS_ 6
#define EPS_  1e-5f

// ---------------------------------------------------------------------------
// LayerNorm: one wave (64 lanes) per row, 4 rows per 256-thread block.
// 1152 = 64 * 18 elements per row -> 18 per lane, shuffle reduction.
// ---------------------------------------------------------------------------
__global__ __launch_bounds__(256)
void ln_kernel(const float* __restrict__ x, const float* __restrict__ g,
               const float* __restrict__ b, float* __restrict__ y)
{
    int row  = blockIdx.x * 4 + (threadIdx.x >> 6);
    int lane = threadIdx.x & 63;
    const float* xr = x + (size_t)row * HID_;
    float v[18];
    float s = 0.f;
#pragma unroll
    for (int i = 0; i < 18; ++i) { v[i] = xr[lane + i * 64]; s += v[i]; }
#pragma unroll
    for (int o = 32; o; o >>= 1) s += __shfl_xor(s, o);
    float mu = s * (1.0f / (float)HID_);
    float vs = 0.f;
#pragma unroll
    for (int i = 0; i < 18; ++i) { float d = v[i] - mu; vs += d * d; }
#pragma unroll
    for (int o = 32; o; o >>= 1) vs += __shfl_xor(vs, o);
    float rstd = rsqrtf(vs * (1.0f / (float)HID_) + EPS_);
    float* yr = y + (size_t)row * HID_;
#pragma unroll
    for (int i = 0; i < 18; ++i) {
        int c = lane + i * 64;
        yr[c] = (v[i] - mu) * rstd * g[c] + b[c];
    }
}

// ---------------------------------------------------------------------------
// GELU (tanh approximation, matches jax.nn.gelu approximate=True)
// ---------------------------------------------------------------------------
__device__ __forceinline__ float gelu_tanh(float x)
{
    float x3 = x * x * x;
    return 0.5f * x * (1.0f + tanhf(0.7978845608028654f * (x + 0.044715f * x3)));
}

// ---------------------------------------------------------------------------
// Tiled fp32 GEMM:  C[M,N] = act(A[M,K] @ B[K,N] + bias[N]) (+ res[M,N])
// 64x64 tile, BK=16, 256 threads, 4x4 micro-tile per thread.
// M is always a multiple of 64 here; N may have a remainder (4304) -> guard N.
// ---------------------------------------------------------------------------
template<int ACT, bool HAS_RES>
__global__ __launch_bounds__(256)
void gemm_kernel(const float* __restrict__ A, const float* __restrict__ B,
                 const float* __restrict__ bias, const float* __restrict__ res,
                 float* __restrict__ C, int M, int N, int K)
{
    __shared__ float As[16][64 + 1];  // [k][m], padded
    __shared__ float Bs[16][64 + 1];  // [k][n], padded
    int tid = threadIdx.x;
    int tx = tid & 15, ty = tid >> 4;
    int bm = blockIdx.y * 64, bn = blockIdx.x * 64;
    float acc[4][4] = {};

    for (int k0 = 0; k0 < K; k0 += 16) {
        {   // A tile: 64 rows x 16 cols (K divisible by 16 for all our calls)
            int kc = tid & 15, mr = tid >> 4;
#pragma unroll
            for (int p = 0; p < 4; ++p) {
                int m = mr + p * 16;
                As[kc][m] = A[(size_t)(bm + m) * K + (k0 + kc)];
            }
        }
        {   // B tile: 16 rows x 64 cols
            int nc = tid & 63, kr = tid >> 6;
#pragma unroll
            for (int p = 0; p < 4; ++p) {
                int k = kr + p * 4;
                int n = bn + nc;
                Bs[k][nc] = (n < N) ? B[(size_t)(k0 + k) * N + n] : 0.0f;
            }
        }
        __syncthreads();
#pragma unroll
        for (int kk = 0; kk < 16; ++kk) {
            float a[4], b[4];
#pragma unroll
            for (int i = 0; i < 4; ++i) a[i] = As[kk][ty * 4 + i];
#pragma unroll
            for (int j = 0; j < 4; ++j) b[j] = Bs[kk][tx * 4 + j];
#pragma unroll
            for (int i = 0; i < 4; ++i)
#pragma unroll
                for (int j = 0; j < 4; ++j)
                    acc[i][j] = fmaf(a[i], b[j], acc[i][j]);
        }
        __syncthreads();
    }

#pragma unroll
    for (int i = 0; i < 4; ++i) {
        int m = bm + ty * 4 + i;
#pragma unroll
        for (int j = 0; j < 4; ++j) {
            int n = bn + tx * 4 + j;
            if (n < N) {
                float v = acc[i][j] + bias[n];
                if (ACT == 1) v = gelu_tanh(v);
                if (HAS_RES) v += res[(size_t)m * N + n];
                C[(size_t)m * N + n] = v;
            }
        }
    }
}

// ---------------------------------------------------------------------------
// RoPE applied in-place to the Q and K thirds of the qkv buffer.
// One thread per (token, part, head, pair): 3072*2*16*36 = 3,538,944 threads.
// ---------------------------------------------------------------------------
__global__ __launch_bounds__(256)
void rope_kernel(float* __restrict__ qkv, const float* __restrict__ fc)
{
    int idx  = blockIdx.x * 256 + threadIdx.x;
    int j    = idx % 36;
    int h    = (idx / 36) % NH_;
    int part = (idx / (36 * NH_)) % 2;
    int t    = idx / (36 * NH_ * 2);
    size_t base = (size_t)t * (3 * HID_) + (size_t)part * HID_ + h * HD_ + 2 * j;
    float a = qkv[base], b = qkv[base + 1];
    float c = fc[t * HD_ + 2 * j], s = fc[t * HD_ + 2 * j + 1];
    qkv[base]     = a * c - b * s;
    qkv[base + 1] = a * s + b * c;
}

// ---------------------------------------------------------------------------
// Attention: one block per (head, 8-query-row tile). Exact two-pass softmax:
// the full 8x3072 fp32 score panel lives in LDS (96 KB). K/V tiles of 64 rows
// are staged through one reused LDS buffer (row stride padded to 73 floats ->
// 2-way-max bank aliasing, which is free on CDNA4).
// NOTE: mask semantics are "+1.0 bias for same segment", softmax over ALL keys.
// ---------------------------------------------------------------------------
__global__ __launch_bounds__(256)
void attn_kernel(const float* __restrict__ qkv, const int* __restrict__ offs,
                 float* __restrict__ out)
{
    __shared__ float Sc[8][S_TOT];     // 96 KB score panel
    __shared__ float Ks[64][HD_ + 1];  // staged K, then reused for V
    __shared__ float Qs[8][HD_];
    __shared__ int   qseg[8];
    __shared__ int   offs_s[SEGS_ + 1];

    int head = blockIdx.x;
    int qt   = blockIdx.y;
    int tid  = threadIdx.x;
    int lane = tid & 63, wv = tid >> 6;

    if (tid < SEGS_ + 1) offs_s[tid] = offs[tid];
    for (int i = tid; i < 8 * HD_; i += 256) {
        int r = i / HD_, d = i % HD_;
        Qs[r][d] = qkv[(size_t)(qt * 8 + r) * (3 * HID_) + head * HD_ + d];
    }
    __syncthreads();
    if (tid < 8) {
        int t = qt * 8 + tid, sg = 0;
#pragma unroll
        for (int i = 1; i <= SEGS_; ++i) sg += (t >= offs_s[i]);
        qseg[tid] = sg;
    }
    __syncthreads();

    const float kscale = 0.11785113019775793f;  // 1/sqrt(72)

    // Phase 1: scores = Q K^T / sqrt(HD) + same-seg bias
    for (int kt = 0; kt < S_TOT / 64; ++kt) {
        for (int i = tid; i < 64 * HD_; i += 256) {
            int r = i / HD_, d = i % HD_;
            Ks[r][d] = qkv[(size_t)(kt * 64 + r) * (3 * HID_) + HID_ + head * HD_ + d];
        }
        __syncthreads();
        int kk = tid & 63, r0 = tid >> 6;
        int t  = kt * 64 + kk;
        int ks = 0;
#pragma unroll
        for (int i = 1; i <= SEGS_; ++i) ks += (t >= offs_s[i]);
#pragma unroll
        for (int rr = 0; rr < 2; ++rr) {
            int r = r0 + rr * 4;
            float acc = 0.f;
#pragma unroll
            for (int d = 0; d < HD_; ++d) acc = fmaf(Qs[r][d], Ks[kk][d], acc);
            Sc[r][t] = acc * kscale + ((qseg[r] == ks) ? 1.0f : 0.0f);
        }
        __syncthreads();
    }

    // Phase 2: softmax per row; wave wv owns rows {wv, wv+4}
#pragma unroll
    for (int rr = 0; rr < 2; ++rr) {
        int r = wv + rr * 4;
        float m = -1e30f;
        for (int t = lane; t < S_TOT; t += 64) m = fmaxf(m, Sc[r][t]);
#pragma unroll
        for (int o = 32; o; o >>= 1) m = fmaxf(m, __shfl_xor(m, o));
        float sum = 0.f;
        for (int t = lane; t < S_TOT; t += 64) {
            float e = __expf(Sc[r][t] - m);
            Sc[r][t] = e;
            sum += e;
        }
#pragma unroll
        for (int o = 32; o; o >>= 1) sum += __shfl_xor(sum, o);
        float inv = 1.0f / sum;
        for (int t = lane; t < S_TOT; t += 64) Sc[r][t] *= inv;
    }
    __syncthreads();

    // Phase 3: out = P @ V. 8*72 = 576 outputs over 256 threads (<=3 each).
    float acc[3] = {0.f, 0.f, 0.f};
    for (int kt = 0; kt < S_TOT / 64; ++kt) {
        for (int i = tid; i < 64 * HD_; i += 256) {
            int r = i / HD_, d = i % HD_;
            Ks[r][d] = qkv[(size_t)(kt * 64 + r) * (3 * HID_) + 2 * HID_ + head * HD_ + d];
        }
        __syncthreads();
#pragma unroll
        for (int oo = 0; oo < 3; ++oo) {
            int o = tid + oo * 256;
            if (o < 8 * HD_) {
                int r = o / HD_, d = o % HD_;
                float a = acc[oo];
#pragma unroll 8
                for (int t = 0; t < 64; ++t)
                    a = fmaf(Sc[r][kt * 64 + t], Ks[t][d], a);
                acc[oo] = a;
            }
        }
        __syncthreads();
    }
#pragma unroll
    for (int oo = 0; oo < 3; ++oo) {
        int o = tid + oo * 256;
        if (o < 8 * HD_) {
            int r = o / HD_, d = o % HD_;
            out[(size_t)(qt * 8 + r) * HID_ + head * HD_ + d] = acc[oo];
        }
    }
}

// ---------------------------------------------------------------------------
// Launch: 8 kernels. Workspace layout (floats), with aliasing:
//   buf0 [3072*1152]        : h  -> aout -> h2
//   buf1 [3072*3456]        : qkv ; after attention, x2 aliases its start
//   buf2 [3072*4304]        : mid (gelu output)
// Total = 3072*(1152+3456+4304)*4 B ~= 109.5 MB
// ---------------------------------------------------------------------------
extern "C" void kernel_launch(void* const* d_in, const int* in_sizes, int n_in,
                              void* d_out, int out_size, void* d_ws, size_t ws_size,
                              hipStream_t stream)
{
    const float* x      = (const float*)d_in[0];
    const int*   offs   = (const int*)  d_in[1];
    const float* fc     = (const float*)d_in[2];
    const float* ln0_g  = (const float*)d_in[3];
    const float* ln0_b  = (const float*)d_in[4];
    const float* wqkv_w = (const float*)d_in[5];
    const float* wqkv_b = (const float*)d_in[6];
    const float* wo_w   = (const float*)d_in[7];
    const float* wo_b   = (const float*)d_in[8];
    const float* ln1_g  = (const float*)d_in[9];
    const float* ln1_b  = (const float*)d_in[10];
    const float* w1     = (const float*)d_in[11];
    const float* b1     = (const float*)d_in[12];
    const float* w2     = (const float*)d_in[13];
    const float* b2     = (const float*)d_in[14];
    float* outp = (float*)d_out;

    float* buf0 = (float*)d_ws;                          // h / aout / h2
    float* qkv  = buf0 + (size_t)S_TOT * HID_;           // qkv ; x2 aliases base
    float* mid  = qkv  + (size_t)S_TOT * 3 * HID_;       // gelu(h2@w1+b1)
    float* h    = buf0;
    float* aout = buf0;
    float* h2   = buf0;
    float* x2   = qkv;   // safe: qkv dead after attention; wo-GEMM reads aout

    // 1. h = LN0(x)
    ln_kernel<<<S_TOT / 4, 256, 0, stream>>>(x, ln0_g, ln0_b, h);
    // 2. qkv = h @ wqkv_w + wqkv_b
    gemm_kernel<0, false><<<dim3(3 * HID_ / 64, S_TOT / 64), 256, 0, stream>>>(
        h, wqkv_w, wqkv_b, nullptr, qkv, S_TOT, 3 * HID_, HID_);
    // 3. RoPE on q,k parts (in place)
    rope_kernel<<<(S_TOT * 2 * NH_ * (HD_ / 2)) / 256, 256, 0, stream>>>(qkv, fc);
    // 4. aout = attention(qkv)
    attn_kernel<<<dim3(NH_, S_TOT / 8), 256, 0, stream>>>(qkv, offs, aout);
    // 5. x2 = x + aout @ wo_w + wo_b
    gemm_kernel<0, true><<<dim3(HID_ / 64, S_TOT / 64), 256, 0, stream>>>(
        aout, wo_w, wo_b, x, x2, S_TOT, HID_, HID_);
    // 6. h2 = LN1(x2)
    ln_kernel<<<S_TOT / 4, 256, 0, stream>>>(x2, ln1_g, ln1_b, h2);
    // 7. mid = gelu(h2 @ w1 + b1)
    gemm_kernel<1, false><<<dim3((MLP_ + 63) / 64, S_TOT / 64), 256, 0, stream>>>(
        h2, w1, b1, nullptr, mid, S_TOT, MLP_, HID_);
    // 8. out = x2 + mid @ w2 + b2
    gemm_kernel<0, true><<<dim3(HID_ / 64, S_TOT / 64), 256, 0, stream>>>(
        mid, w2, b2, x2, outp, S_TOT, HID_, MLP_);
}

// Round 2
// 2538.826 us; speedup vs baseline: 4.0303x; 4.0303x over previous
//
#include <hip/hip_runtime.h>
#include <hip/hip_bf16.h>
#include <cstddef>

// Problem constants
#define S_TOT 3072
#define HID_  1152
#define MLP_  4304
#define NH_   16
#define HD_   72
#define SEGS_ 6
#define EPS_  1e-5f

typedef __attribute__((ext_vector_type(8))) short short8;
typedef __attribute__((ext_vector_type(4))) float floatx4;

__device__ __forceinline__ unsigned short f2bf(float x)
{
    __hip_bfloat16 h = __float2bfloat16(x);
    return *reinterpret_cast<unsigned short*>(&h);
}

// ---------------------------------------------------------------------------
// LayerNorm: one wave per row, 4 rows per 256-thread block.
// ---------------------------------------------------------------------------
__global__ __launch_bounds__(256)
void ln_kernel(const float* __restrict__ x, const float* __restrict__ g,
               const float* __restrict__ b, float* __restrict__ y)
{
    int row  = blockIdx.x * 4 + (threadIdx.x >> 6);
    int lane = threadIdx.x & 63;
    const float* xr = x + (size_t)row * HID_;
    float v[18];
    float s = 0.f;
#pragma unroll
    for (int i = 0; i < 18; ++i) { v[i] = xr[lane + i * 64]; s += v[i]; }
#pragma unroll
    for (int o = 32; o; o >>= 1) s += __shfl_xor(s, o);
    float mu = s * (1.0f / (float)HID_);
    float vs = 0.f;
#pragma unroll
    for (int i = 0; i < 18; ++i) { float d = v[i] - mu; vs += d * d; }
#pragma unroll
    for (int o = 32; o; o >>= 1) vs += __shfl_xor(vs, o);
    float rstd = rsqrtf(vs * (1.0f / (float)HID_) + EPS_);
    float* yr = y + (size_t)row * HID_;
#pragma unroll
    for (int i = 0; i < 18; ++i) {
        int c = lane + i * 64;
        yr[c] = (v[i] - mu) * rstd * g[c] + b[c];
    }
}

__device__ __forceinline__ float gelu_tanh(float x)
{
    float x3 = x * x * x;
    return 0.5f * x * (1.0f + tanhf(0.7978845608028654f * (x + 0.044715f * x3)));
}

// ---------------------------------------------------------------------------
// Tiled fp32 GEMM (unchanged from round 0)
// ---------------------------------------------------------------------------
template<int ACT, bool HAS_RES>
__global__ __launch_bounds__(256)
void gemm_kernel(const float* __restrict__ A, const float* __restrict__ B,
                 const float* __restrict__ bias, const float* __restrict__ res,
                 float* __restrict__ C, int M, int N, int K)
{
    __shared__ float As[16][64 + 1];
    __shared__ float Bs[16][64 + 1];
    int tid = threadIdx.x;
    int tx = tid & 15, ty = tid >> 4;
    int bm = blockIdx.y * 64, bn = blockIdx.x * 64;
    float acc[4][4] = {};

    for (int k0 = 0; k0 < K; k0 += 16) {
        {
            int kc = tid & 15, mr = tid >> 4;
#pragma unroll
            for (int p = 0; p < 4; ++p) {
                int m = mr + p * 16;
                As[kc][m] = A[(size_t)(bm + m) * K + (k0 + kc)];
            }
        }
        {
            int nc = tid & 63, kr = tid >> 6;
#pragma unroll
            for (int p = 0; p < 4; ++p) {
                int k = kr + p * 4;
                int n = bn + nc;
                Bs[k][nc] = (n < N) ? B[(size_t)(k0 + k) * N + n] : 0.0f;
            }
        }
        __syncthreads();
#pragma unroll
        for (int kk = 0; kk < 16; ++kk) {
            float a[4], b[4];
#pragma unroll
            for (int i = 0; i < 4; ++i) a[i] = As[kk][ty * 4 + i];
#pragma unroll
            for (int j = 0; j < 4; ++j) b[j] = Bs[kk][tx * 4 + j];
#pragma unroll
            for (int i = 0; i < 4; ++i)
#pragma unroll
                for (int j = 0; j < 4; ++j)
                    acc[i][j] = fmaf(a[i], b[j], acc[i][j]);
        }
        __syncthreads();
    }

#pragma unroll
    for (int i = 0; i < 4; ++i) {
        int m = bm + ty * 4 + i;
#pragma unroll
        for (int j = 0; j < 4; ++j) {
            int n = bn + tx * 4 + j;
            if (n < N) {
                float v = acc[i][j] + bias[n];
                if (ACT == 1) v = gelu_tanh(v);
                if (HAS_RES) v += res[(size_t)m * N + n];
                C[(size_t)m * N + n] = v;
            }
        }
    }
}

// ---------------------------------------------------------------------------
// RoPE in-place on Q,K thirds of qkv (unchanged)
// ---------------------------------------------------------------------------
__global__ __launch_bounds__(256)
void rope_kernel(float* __restrict__ qkv, const float* __restrict__ fc)
{
    int idx  = blockIdx.x * 256 + threadIdx.x;
    int j    = idx % 36;
    int h    = (idx / 36) % NH_;
    int part = (idx / (36 * NH_)) % 2;
    int t    = idx / (36 * NH_ * 2);
    size_t base = (size_t)t * (3 * HID_) + (size_t)part * HID_ + h * HD_ + 2 * j;
    float a = qkv[base], b = qkv[base + 1];
    float c = fc[t * HD_ + 2 * j], s = fc[t * HD_ + 2 * j + 1];
    qkv[base]     = a * c - b * s;
    qkv[base + 1] = a * s + b * c;
}

// ---------------------------------------------------------------------------
// Flash-style MFMA attention.
// Block = (64-query tile qt = blockIdx.x, head = blockIdx.y), 4 waves.
// Wave w owns query-row strip [w*16, w*16+16).
// mfma_f32_16x16x32_bf16 layouts (verified, learn_hip m89):
//   A: row = lane%16,          k  = 8*(lane/16) + i   (8 bf16, contiguous k)
//   B: col = lane%16,          k  = 8*(lane/16) + i
//   D: row = (lane/16)*4 + r,  col = lane%16
// HD=72 padded to K=96 (QK^T) and N=80 (PV) with zeros.
// Softmax: fp32 online (running m,l per row); mask = +1.0 same-segment bias.
// P re-fragmented for PV via wave-private LDS strip (no barrier needed).
// LDS = 47.4 KB -> 3 blocks/CU.
// ---------------------------------------------------------------------------
#define QBLK 64
#define KVBLK 64
#define QKS 104   // Qs/Ks row stride (bf16): 208 B -> 2-way (free) on b128 reads
#define VTS 72    // Vt row stride (bf16): 144 B -> 2-way (free) on b128 reads
#define PLS 72    // P_lds row stride

__global__ __launch_bounds__(256)
void attn_mfma_kernel(const float* __restrict__ qkv, const int* __restrict__ offs,
                      float* __restrict__ out)
{
    __shared__ unsigned short Qs[QBLK][QKS];   // 13312 B
    __shared__ unsigned short Ks[KVBLK][QKS];  // 13312 B
    __shared__ unsigned short Vt[80][VTS];     // 11520 B  [d][key]
    __shared__ unsigned short Pl[QBLK][PLS];   //  9216 B

    const int qt   = blockIdx.x;
    const int head = blockIdx.y;
    const int tid  = threadIdx.x;
    const int lane = tid & 63;
    const int wv   = tid >> 6;
    const int lm   = lane & 15;   // col / row-in-strip selector
    const int lg   = lane >> 4;   // k-block / row-group selector
    const int q0   = qt * QBLK;

    // segment offsets (7 ints), fully unrolled into registers
    int ofv[SEGS_ + 1];
#pragma unroll
    for (int i = 0; i <= SEGS_; ++i) ofv[i] = offs[i];

    // ---- stage Q (once) + zero pads ----
    for (int i = tid; i < QBLK * HD_; i += 256) {
        int r = i / HD_, d = i % HD_;
        Qs[r][d] = f2bf(qkv[(size_t)(q0 + r) * (3 * HID_) + head * HD_ + d]);
    }
    for (int i = tid; i < QBLK * (QKS - HD_); i += 256) {
        int r = i / (QKS - HD_), d = i % (QKS - HD_);
        Qs[r][HD_ + d] = 0;
        Ks[r][HD_ + d] = 0;
    }
    for (int i = tid; i < 8 * VTS; i += 256) {
        Vt[72 + i / VTS][i % VTS] = 0;
    }
    __syncthreads();

    // Q fragments: reused for all 48 kv tiles
    short8 qf[3];
#pragma unroll
    for (int ks = 0; ks < 3; ++ks)
        qf[ks] = *reinterpret_cast<const short8*>(&Qs[wv * 16 + lm][ks * 32 + 8 * lg]);

    // segment of each of this lane's 4 query rows
    int qsegr[4];
#pragma unroll
    for (int r = 0; r < 4; ++r) {
        int t = q0 + wv * 16 + lg * 4 + r;
        int sg = 0;
#pragma unroll
        for (int i = 1; i <= SEGS_; ++i) sg += (t >= ofv[i]);
        qsegr[r] = sg;
    }

    const float kscale = 0.11785113019775793f;  // 1/sqrt(72)

    floatx4 of[5] = {};            // O accumulator: 5 col-tiles x 4 rows
    float   m_r[4], l_r[4];
#pragma unroll
    for (int r = 0; r < 4; ++r) { m_r[r] = -1e30f; l_r[r] = 0.f; }

    for (int kt = 0; kt < S_TOT / KVBLK; ++kt) {
        const int kv0 = kt * KVBLK;
        // ---- stage K tile (row-major) and V tile (transposed) ----
        for (int i = tid; i < KVBLK * HD_; i += 256) {
            int r = i / HD_, d = i % HD_;
            size_t base = (size_t)(kv0 + r) * (3 * HID_) + head * HD_ + d;
            Ks[r][d] = f2bf(qkv[base + HID_]);
            Vt[d][r] = f2bf(qkv[base + 2 * HID_]);
        }
        __syncthreads();

        // ---- S = Q K^T (fp32 accum) ----
        floatx4 sf[4];
#pragma unroll
        for (int ct = 0; ct < 4; ++ct) {
            floatx4 acc = {0.f, 0.f, 0.f, 0.f};
#pragma unroll
            for (int ks = 0; ks < 3; ++ks) {
                short8 kb = *reinterpret_cast<const short8*>(&Ks[ct * 16 + lm][ks * 32 + 8 * lg]);
                acc = __builtin_amdgcn_mfma_f32_16x16x32_bf16(qf[ks], kb, acc, 0, 0, 0);
            }
            sf[ct] = acc;
        }

        // ---- scale + segment bias ----
#pragma unroll
        for (int ct = 0; ct < 4; ++ct) {
            int tcol = kv0 + ct * 16 + lm;
            int ksg = 0;
#pragma unroll
            for (int i = 1; i <= SEGS_; ++i) ksg += (tcol >= ofv[i]);
#pragma unroll
            for (int r = 0; r < 4; ++r)
                sf[ct][r] = sf[ct][r] * kscale + ((qsegr[r] == ksg) ? 1.0f : 0.0f);
        }

        // ---- online softmax ----
        float rm[4], rs[4], sc[4];
#pragma unroll
        for (int r = 0; r < 4; ++r) {
            float mx = fmaxf(fmaxf(sf[0][r], sf[1][r]), fmaxf(sf[2][r], sf[3][r]));
            mx = fmaxf(mx, __shfl_xor(mx, 1));
            mx = fmaxf(mx, __shfl_xor(mx, 2));
            mx = fmaxf(mx, __shfl_xor(mx, 4));
            mx = fmaxf(mx, __shfl_xor(mx, 8));
            rm[r] = mx;
            float mn = fmaxf(m_r[r], mx);
            sc[r] = __expf(m_r[r] - mn);
            m_r[r] = mn;
        }
#pragma unroll
        for (int r = 0; r < 4; ++r) rs[r] = 0.f;
#pragma unroll
        for (int ct = 0; ct < 4; ++ct)
#pragma unroll
            for (int r = 0; r < 4; ++r) {
                float p = __expf(sf[ct][r] - m_r[r]);
                sf[ct][r] = p;
                rs[r] += p;
            }
#pragma unroll
        for (int r = 0; r < 4; ++r) {
            float s = rs[r];
            s += __shfl_xor(s, 1);
            s += __shfl_xor(s, 2);
            s += __shfl_xor(s, 4);
            s += __shfl_xor(s, 8);
            l_r[r] = l_r[r] * sc[r] + s;
        }
        // rescale O
#pragma unroll
        for (int ct = 0; ct < 5; ++ct)
#pragma unroll
            for (int r = 0; r < 4; ++r) of[ct][r] *= sc[r];

        // ---- P -> LDS (bf16), wave-private strip, re-fragment as A ----
#pragma unroll
        for (int ct = 0; ct < 4; ++ct)
#pragma unroll
            for (int r = 0; r < 4; ++r)
                Pl[wv * 16 + lg * 4 + r][ct * 16 + lm] = f2bf(sf[ct][r]);

        short8 pa0 = *reinterpret_cast<const short8*>(&Pl[wv * 16 + lm][8 * lg]);
        short8 pa1 = *reinterpret_cast<const short8*>(&Pl[wv * 16 + lm][32 + 8 * lg]);

        // ---- O += P @ V ----
#pragma unroll
        for (int ct = 0; ct < 5; ++ct) {
            short8 v0 = *reinterpret_cast<const short8*>(&Vt[ct * 16 + lm][8 * lg]);
            short8 v1 = *reinterpret_cast<const short8*>(&Vt[ct * 16 + lm][32 + 8 * lg]);
            of[ct] = __builtin_amdgcn_mfma_f32_16x16x32_bf16(pa0, v0, of[ct], 0, 0, 0);
            of[ct] = __builtin_amdgcn_mfma_f32_16x16x32_bf16(pa1, v1, of[ct], 0, 0, 0);
        }
        __syncthreads();  // all reads of Ks/Vt done before next stage
    }

    // ---- epilogue: out = O / l ----
    float inv[4];
#pragma unroll
    for (int r = 0; r < 4; ++r) inv[r] = 1.0f / l_r[r];
#pragma unroll
    for (int ct = 0; ct < 5; ++ct) {
        int d = ct * 16 + lm;
        if (d < HD_) {
#pragma unroll
            for (int r = 0; r < 4; ++r) {
                int row = q0 + wv * 16 + lg * 4 + r;
                out[(size_t)row * HID_ + head * HD_ + d] = of[ct][r] * inv[r];
            }
        }
    }
}

// ---------------------------------------------------------------------------
// Launch
// ---------------------------------------------------------------------------
extern "C" void kernel_launch(void* const* d_in, const int* in_sizes, int n_in,
                              void* d_out, int out_size, void* d_ws, size_t ws_size,
                              hipStream_t stream)
{
    const float* x      = (const float*)d_in[0];
    const int*   offs   = (const int*)  d_in[1];
    const float* fc     = (const float*)d_in[2];
    const float* ln0_g  = (const float*)d_in[3];
    const float* ln0_b  = (const float*)d_in[4];
    const float* wqkv_w = (const float*)d_in[5];
    const float* wqkv_b = (const float*)d_in[6];
    const float* wo_w   = (const float*)d_in[7];
    const float* wo_b   = (const float*)d_in[8];
    const float* ln1_g  = (const float*)d_in[9];
    const float* ln1_b  = (const float*)d_in[10];
    const float* w1     = (const float*)d_in[11];
    const float* b1     = (const float*)d_in[12];
    const float* w2     = (const float*)d_in[13];
    const float* b2     = (const float*)d_in[14];
    float* outp = (float*)d_out;

    float* buf0 = (float*)d_ws;                          // h / aout / h2
    float* qkv  = buf0 + (size_t)S_TOT * HID_;
    float* mid  = qkv  + (size_t)S_TOT * 3 * HID_;
    float* h    = buf0;
    float* aout = buf0;
    float* h2   = buf0;
    float* x2   = qkv;   // qkv dead after attention

    ln_kernel<<<S_TOT / 4, 256, 0, stream>>>(x, ln0_g, ln0_b, h);
    gemm_kernel<0, false><<<dim3(3 * HID_ / 64, S_TOT / 64), 256, 0, stream>>>(
        h, wqkv_w, wqkv_b, nullptr, qkv, S_TOT, 3 * HID_, HID_);
    rope_kernel<<<(S_TOT * 2 * NH_ * (HD_ / 2)) / 256, 256, 0, stream>>>(qkv, fc);
    attn_mfma_kernel<<<dim3(S_TOT / QBLK, NH_), 256, 0, stream>>>(qkv, offs, aout);
    gemm_kernel<0, true><<<dim3(HID_ / 64, S_TOT / 64), 256, 0, stream>>>(
        aout, wo_w, wo_b, x, x2, S_TOT, HID_, HID_);
    ln_kernel<<<S_TOT / 4, 256, 0, stream>>>(x2, ln1_g, ln1_b, h2);
    gemm_kernel<1, false><<<dim3((MLP_ + 63) / 64, S_TOT / 64), 256, 0, stream>>>(
        h2, w1, b1, nullptr, mid, S_TOT, MLP_, HID_);
    gemm_kernel<0, true><<<dim3(HID_ / 64, S_TOT / 64), 256, 0, stream>>>(
        mid, w2, b2, x2, outp, S_TOT, HID_, MLP_);
}

// Round 4
// 874.618 us; speedup vs baseline: 11.6992x; 2.9028x over previous
//
#include <hip/hip_runtime.h>
#include <hip/hip_bf16.h>
#include <cstddef>

// Problem constants
#define S_TOT 3072
#define HID_  1152
#define MLP_  4304
#define MLPP_ 4352   // MLP padded to multiple of 128 (pad is exact zeros)
#define NH_   16
#define HD_   72
#define SEGS_ 6
#define EPS_  1e-5f

typedef __attribute__((ext_vector_type(8))) short short8;
typedef __attribute__((ext_vector_type(4))) float floatx4;
typedef unsigned short ushort;

__device__ __forceinline__ ushort f2bf(float x)
{
    __hip_bfloat16 h = __float2bfloat16(x);
    return *reinterpret_cast<ushort*>(&h);
}
__device__ __forceinline__ float bf2f(ushort u)
{
    __hip_bfloat16 h = *reinterpret_cast<__hip_bfloat16*>(&u);
    return __bfloat162float(h);
}

__device__ __forceinline__ float gelu_tanh(float x)
{
    float x3 = x * x * x;
    return 0.5f * x * (1.0f + tanhf(0.7978845608028654f * (x + 0.044715f * x3)));
}

// ---------------------------------------------------------------------------
// LayerNorm -> split bf16 (hi, lo) output. One wave per row.
// ---------------------------------------------------------------------------
__global__ __launch_bounds__(256)
void ln_bf_kernel(const float* __restrict__ x, const float* __restrict__ g,
                  const float* __restrict__ b, ushort* __restrict__ yh,
                  ushort* __restrict__ yl)
{
    int row  = blockIdx.x * 4 + (threadIdx.x >> 6);
    int lane = threadIdx.x & 63;
    const float* xr = x + (size_t)row * HID_;
    float v[18];
    float s = 0.f;
#pragma unroll
    for (int i = 0; i < 18; ++i) { v[i] = xr[lane + i * 64]; s += v[i]; }
#pragma unroll
    for (int o = 32; o; o >>= 1) s += __shfl_xor(s, o);
    float mu = s * (1.0f / (float)HID_);
    float vs = 0.f;
#pragma unroll
    for (int i = 0; i < 18; ++i) { float d = v[i] - mu; vs += d * d; }
#pragma unroll
    for (int o = 32; o; o >>= 1) vs += __shfl_xor(vs, o);
    float rstd = rsqrtf(vs * (1.0f / (float)HID_) + EPS_);
#pragma unroll
    for (int i = 0; i < 18; ++i) {
        int c = lane + i * 64;
        float val = (v[i] - mu) * rstd * g[c] + b[c];
        ushort hi = f2bf(val);
        yh[(size_t)row * HID_ + c] = hi;
        yl[(size_t)row * HID_ + c] = f2bf(val - bf2f(hi));
    }
}

// ---------------------------------------------------------------------------
// Weight convert + transpose: in fp32 [Kin][Nin] -> out bf16 hi/lo [Nout][Kout]
// (transposed, zero-padded). Grid: (Nout/32, Kout/32), 256 threads.
// ---------------------------------------------------------------------------
__global__ __launch_bounds__(256)
void convt_kernel(const float* __restrict__ in, ushort* __restrict__ oh,
                  ushort* __restrict__ ol, int Kin, int Nin, int Kout)
{
    __shared__ float t[32][33];
    int n0 = blockIdx.x * 32, k0 = blockIdx.y * 32;
    int tx = threadIdx.x & 31, ty = threadIdx.x >> 5;  // ty 0..7
#pragma unroll
    for (int j = 0; j < 4; ++j) {
        int k = k0 + ty + 8 * j, n = n0 + tx;
        t[ty + 8 * j][tx] = (k < Kin && n < Nin) ? in[(size_t)k * Nin + n] : 0.f;
    }
    __syncthreads();
#pragma unroll
    for (int j = 0; j < 4; ++j) {
        int n = n0 + ty + 8 * j, k = k0 + tx;
        float v = t[tx][ty + 8 * j];
        ushort hi = f2bf(v);
        oh[(size_t)n * Kout + k] = hi;
        ol[(size_t)n * Kout + k] = f2bf(v - bf2f(hi));
    }
}

// ---------------------------------------------------------------------------
// Split-bf16 MFMA GEMM: C = act(A @ B^T_weights + bias) (+res)
//   A: hi/lo bf16 [M][K]   B: hi/lo bf16 [Npad][K] (pre-transposed weights)
//   C ~= Ah Bh + Al Bh + Ah Bl   (fp32-class accuracy)
// 128x128 tile, BK=32, 4 waves (2x2), 4x4 fragments of 16x16x32 per wave.
// LDS [128][32] bf16 per tile, XOR-swizzled: elem ^= (row&7)<<3.
// ---------------------------------------------------------------------------
__device__ __forceinline__ int swz(int row, int ke)
{
    return (row * 32 + ke) ^ ((row & 7) << 3);
}

template<int ACT, bool HAS_RES, bool OUT_PAIR>
__global__ __launch_bounds__(256)
void gemm_bf16x3_kernel(const ushort* __restrict__ Ah, const ushort* __restrict__ Al,
                        const ushort* __restrict__ Bh, const ushort* __restrict__ Bl,
                        const float* __restrict__ bias, const float* __restrict__ res,
                        float* __restrict__ C, ushort* __restrict__ Chi,
                        ushort* __restrict__ Clo, int M, int N, int K, int Ns)
{
    __shared__ ushort sAh[128 * 32], sAl[128 * 32], sBh[128 * 32], sBl[128 * 32];

    const int tid = threadIdx.x;
    const int bm = blockIdx.y * 128, bn = blockIdx.x * 128;
    const int lane = tid & 63, wv = tid >> 6;
    const int lm = lane & 15, lg = lane >> 4;
    const int wr = wv >> 1, wc = wv & 1;

    const int srow = tid >> 2, skb = (tid & 3) * 8;
    const size_t aoff0 = (size_t)(bm + srow) * K + skb;
    const size_t aoff1 = (size_t)(bm + srow + 64) * K + skb;
    const size_t boff0 = (size_t)(bn + srow) * K + skb;
    const size_t boff1 = (size_t)(bn + srow + 64) * K + skb;

    short8 rAh0, rAh1, rAl0, rAl1, rBh0, rBh1, rBl0, rBl1;
    auto LOAD = [&](int k0) {
        rAh0 = *reinterpret_cast<const short8*>(Ah + aoff0 + k0);
        rAh1 = *reinterpret_cast<const short8*>(Ah + aoff1 + k0);
        rAl0 = *reinterpret_cast<const short8*>(Al + aoff0 + k0);
        rAl1 = *reinterpret_cast<const short8*>(Al + aoff1 + k0);
        rBh0 = *reinterpret_cast<const short8*>(Bh + boff0 + k0);
        rBh1 = *reinterpret_cast<const short8*>(Bh + boff1 + k0);
        rBl0 = *reinterpret_cast<const short8*>(Bl + boff0 + k0);
        rBl1 = *reinterpret_cast<const short8*>(Bl + boff1 + k0);
    };

    floatx4 acc[4][4] = {};
    LOAD(0);

    const int w0 = swz(srow, skb), w1 = swz(srow + 64, skb);
    for (int k0 = 0; k0 < K; k0 += 32) {
        *reinterpret_cast<short8*>(&sAh[w0]) = rAh0;
        *reinterpret_cast<short8*>(&sAh[w1]) = rAh1;
        *reinterpret_cast<short8*>(&sAl[w0]) = rAl0;
        *reinterpret_cast<short8*>(&sAl[w1]) = rAl1;
        *reinterpret_cast<short8*>(&sBh[w0]) = rBh0;
        *reinterpret_cast<short8*>(&sBh[w1]) = rBh1;
        *reinterpret_cast<short8*>(&sBl[w0]) = rBl0;
        *reinterpret_cast<short8*>(&sBl[w1]) = rBl1;
        __syncthreads();
        if (k0 + 32 < K) LOAD(k0 + 32);

        short8 bhf[4], blf[4];
#pragma unroll
        for (int j = 0; j < 4; ++j) {
            int o = swz(wc * 64 + j * 16 + lm, 8 * lg);
            bhf[j] = *reinterpret_cast<const short8*>(&sBh[o]);
            blf[j] = *reinterpret_cast<const short8*>(&sBl[o]);
        }
#pragma unroll
        for (int i = 0; i < 4; ++i) {
            int o = swz(wr * 64 + i * 16 + lm, 8 * lg);
            short8 ahf = *reinterpret_cast<const short8*>(&sAh[o]);
            short8 alf = *reinterpret_cast<const short8*>(&sAl[o]);
#pragma unroll
            for (int j = 0; j < 4; ++j) {
                acc[i][j] = __builtin_amdgcn_mfma_f32_16x16x32_bf16(ahf, bhf[j], acc[i][j], 0, 0, 0);
                acc[i][j] = __builtin_amdgcn_mfma_f32_16x16x32_bf16(alf, bhf[j], acc[i][j], 0, 0, 0);
                acc[i][j] = __builtin_amdgcn_mfma_f32_16x16x32_bf16(ahf, blf[j], acc[i][j], 0, 0, 0);
            }
        }
        __syncthreads();
    }

#pragma unroll
    for (int i = 0; i < 4; ++i) {
#pragma unroll
        for (int j = 0; j < 4; ++j) {
#pragma unroll
            for (int r = 0; r < 4; ++r) {
                int m = bm + wr * 64 + i * 16 + lg * 4 + r;
                int n = bn + wc * 64 + j * 16 + lm;
                if (OUT_PAIR) {
                    float v = 0.f;
                    if (n < N) {
                        v = acc[i][j][r] + bias[n];
                        if (ACT == 1) v = gelu_tanh(v);
                    }
                    ushort hi = f2bf(v);
                    Chi[(size_t)m * Ns + n] = hi;
                    Clo[(size_t)m * Ns + n] = f2bf(v - bf2f(hi));
                } else if (n < N) {
                    float v = acc[i][j][r] + bias[n];
                    if (ACT == 1) v = gelu_tanh(v);
                    if (HAS_RES) v += res[(size_t)m * Ns + n];
                    C[(size_t)m * Ns + n] = v;
                }
            }
        }
    }
}

// ---------------------------------------------------------------------------
// RoPE in-place on Q,K thirds of qkv (fp32)
// ---------------------------------------------------------------------------
__global__ __launch_bounds__(256)
void rope_kernel(float* __restrict__ qkv, const float* __restrict__ fc)
{
    int idx  = blockIdx.x * 256 + threadIdx.x;
    int j    = idx % 36;
    int h    = (idx / 36) % NH_;
    int part = (idx / (36 * NH_)) % 2;
    int t    = idx / (36 * NH_ * 2);
    size_t base = (size_t)t * (3 * HID_) + (size_t)part * HID_ + h * HD_ + 2 * j;
    float a = qkv[base], b = qkv[base + 1];
    float c = fc[t * HD_ + 2 * j], s = fc[t * HD_ + 2 * j + 1];
    qkv[base]     = a * c - b * s;
    qkv[base + 1] = a * s + b * c;
}

// ---------------------------------------------------------------------------
// Flash-style MFMA attention (epilogue emits hi/lo bf16).
// ---------------------------------------------------------------------------
#define QBLK 64
#define KVBLK 64
#define QKS 104
#define VTS 72
#define PLS 72

__global__ __launch_bounds__(256)
void attn_mfma_kernel(const float* __restrict__ qkv, const int* __restrict__ offs,
                      ushort* __restrict__ oh, ushort* __restrict__ ol)
{
    __shared__ ushort Qs[QBLK][QKS];
    __shared__ ushort Ks[KVBLK][QKS];
    __shared__ ushort Vt[80][VTS];
    __shared__ ushort Pl[QBLK][PLS];

    const int qt   = blockIdx.x;
    const int head = blockIdx.y;
    const int tid  = threadIdx.x;
    const int lane = tid & 63;
    const int wv   = tid >> 6;
    const int lm   = lane & 15;
    const int lg   = lane >> 4;
    const int q0   = qt * QBLK;

    int ofv[SEGS_ + 1];
#pragma unroll
    for (int i = 0; i <= SEGS_; ++i) ofv[i] = offs[i];

    for (int i = tid; i < QBLK * HD_; i += 256) {
        int r = i / HD_, d = i % HD_;
        Qs[r][d] = f2bf(qkv[(size_t)(q0 + r) * (3 * HID_) + head * HD_ + d]);
    }
    for (int i = tid; i < QBLK * (QKS - HD_); i += 256) {
        int r = i / (QKS - HD_), d = i % (QKS - HD_);
        Qs[r][HD_ + d] = 0;
        Ks[r][HD_ + d] = 0;
    }
    for (int i = tid; i < 8 * VTS; i += 256) {
        Vt[72 + i / VTS][i % VTS] = 0;
    }
    __syncthreads();

    short8 qf[3];
#pragma unroll
    for (int ks = 0; ks < 3; ++ks)
        qf[ks] = *reinterpret_cast<const short8*>(&Qs[wv * 16 + lm][ks * 32 + 8 * lg]);

    int qsegr[4];
#pragma unroll
    for (int r = 0; r < 4; ++r) {
        int t = q0 + wv * 16 + lg * 4 + r;
        int sg = 0;
#pragma unroll
        for (int i = 1; i <= SEGS_; ++i) sg += (t >= ofv[i]);
        qsegr[r] = sg;
    }

    const float kscale = 0.11785113019775793f;

    floatx4 of[5] = {};
    float   m_r[4], l_r[4];
#pragma unroll
    for (int r = 0; r < 4; ++r) { m_r[r] = -1e30f; l_r[r] = 0.f; }

    for (int kt = 0; kt < S_TOT / KVBLK; ++kt) {
        const int kv0 = kt * KVBLK;
        for (int i = tid; i < KVBLK * HD_; i += 256) {
            int r = i / HD_, d = i % HD_;
            size_t base = (size_t)(kv0 + r) * (3 * HID_) + head * HD_ + d;
            Ks[r][d] = f2bf(qkv[base + HID_]);
            Vt[d][r] = f2bf(qkv[base + 2 * HID_]);
        }
        __syncthreads();

        floatx4 sf[4];
#pragma unroll
        for (int ct = 0; ct < 4; ++ct) {
            floatx4 acc = {0.f, 0.f, 0.f, 0.f};
#pragma unroll
            for (int ks = 0; ks < 3; ++ks) {
                short8 kb = *reinterpret_cast<const short8*>(&Ks[ct * 16 + lm][ks * 32 + 8 * lg]);
                acc = __builtin_amdgcn_mfma_f32_16x16x32_bf16(qf[ks], kb, acc, 0, 0, 0);
            }
            sf[ct] = acc;
        }

#pragma unroll
        for (int ct = 0; ct < 4; ++ct) {
            int tcol = kv0 + ct * 16 + lm;
            int ksg = 0;
#pragma unroll
            for (int i = 1; i <= SEGS_; ++i) ksg += (tcol >= ofv[i]);
#pragma unroll
            for (int r = 0; r < 4; ++r)
                sf[ct][r] = sf[ct][r] * kscale + ((qsegr[r] == ksg) ? 1.0f : 0.0f);
        }

        float rs[4], sc[4];
#pragma unroll
        for (int r = 0; r < 4; ++r) {
            float mx = fmaxf(fmaxf(sf[0][r], sf[1][r]), fmaxf(sf[2][r], sf[3][r]));
            mx = fmaxf(mx, __shfl_xor(mx, 1));
            mx = fmaxf(mx, __shfl_xor(mx, 2));
            mx = fmaxf(mx, __shfl_xor(mx, 4));
            mx = fmaxf(mx, __shfl_xor(mx, 8));
            float mn = fmaxf(m_r[r], mx);
            sc[r] = __expf(m_r[r] - mn);
            m_r[r] = mn;
        }
#pragma unroll
        for (int r = 0; r < 4; ++r) rs[r] = 0.f;
#pragma unroll
        for (int ct = 0; ct < 4; ++ct)
#pragma unroll
            for (int r = 0; r < 4; ++r) {
                float p = __expf(sf[ct][r] - m_r[r]);
                sf[ct][r] = p;
                rs[r] += p;
            }
#pragma unroll
        for (int r = 0; r < 4; ++r) {
            float s = rs[r];
            s += __shfl_xor(s, 1);
            s += __shfl_xor(s, 2);
            s += __shfl_xor(s, 4);
            s += __shfl_xor(s, 8);
            l_r[r] = l_r[r] * sc[r] + s;
        }
#pragma unroll
        for (int ct = 0; ct < 5; ++ct)
#pragma unroll
            for (int r = 0; r < 4; ++r) of[ct][r] *= sc[r];

#pragma unroll
        for (int ct = 0; ct < 4; ++ct)
#pragma unroll
            for (int r = 0; r < 4; ++r)
                Pl[wv * 16 + lg * 4 + r][ct * 16 + lm] = f2bf(sf[ct][r]);

        short8 pa0 = *reinterpret_cast<const short8*>(&Pl[wv * 16 + lm][8 * lg]);
        short8 pa1 = *reinterpret_cast<const short8*>(&Pl[wv * 16 + lm][32 + 8 * lg]);

#pragma unroll
        for (int ct = 0; ct < 5; ++ct) {
            short8 v0 = *reinterpret_cast<const short8*>(&Vt[ct * 16 + lm][8 * lg]);
            short8 v1 = *reinterpret_cast<const short8*>(&Vt[ct * 16 + lm][32 + 8 * lg]);
            of[ct] = __builtin_amdgcn_mfma_f32_16x16x32_bf16(pa0, v0, of[ct], 0, 0, 0);
            of[ct] = __builtin_amdgcn_mfma_f32_16x16x32_bf16(pa1, v1, of[ct], 0, 0, 0);
        }
        __syncthreads();
    }

    float inv[4];
#pragma unroll
    for (int r = 0; r < 4; ++r) inv[r] = 1.0f / l_r[r];
#pragma unroll
    for (int ct = 0; ct < 5; ++ct) {
        int d = ct * 16 + lm;
        if (d < HD_) {
#pragma unroll
            for (int r = 0; r < 4; ++r) {
                int row = q0 + wv * 16 + lg * 4 + r;
                float v = of[ct][r] * inv[r];
                ushort hi = f2bf(v);
                oh[(size_t)row * HID_ + head * HD_ + d] = hi;
                ol[(size_t)row * HID_ + head * HD_ + d] = f2bf(v - bf2f(hi));
            }
        }
    }
}

// ---------------------------------------------------------------------------
// Launch. Workspace: liveness-aliased static layout, peak = 101,842,944 B
// (< the 109.5 MB footprint proven to fit in rounds 0/2).
//
// Timeline (single stream; Lk = launch k):
//  L1 convt wqkv -> W [56.6M,72.5M)      L7  gemm x2   <- aout,WO  -> X2 [0,14.2M)
//  L2 ln0       -> H [42.5M,56.6M)      L8  ln1       -> H2 [14.2M,28.3M)
//  L3 gemm qkv  <- H,W -> QKV [0,42.5M)  L9  convt w1  -> W1 [28.3M,48.4M)
//  L4 rope      (QKV in place)           L10 gemm mid  <- H2,W1 -> MID [48.4M,101.8M)
//  L5 attn      <- QKV -> AOUT=H addr    L11 convt w2  -> W2 [14.2M,34.2M)
//  L6 convt wo  -> WO [14.2M,19.5M)      L12 gemm out  <- MID,W2,X2 -> d_out
// Every same-launch read/write pair is disjoint; every reuse is
// write-after-last-use in stream order.
// ---------------------------------------------------------------------------
extern "C" void kernel_launch(void* const* d_in, const int* in_sizes, int n_in,
                              void* d_out, int out_size, void* d_ws, size_t ws_size,
                              hipStream_t stream)
{
    const float* x      = (const float*)d_in[0];
    const int*   offs   = (const int*)  d_in[1];
    const float* fc     = (const float*)d_in[2];
    const float* ln0_g  = (const float*)d_in[3];
    const float* ln0_b  = (const float*)d_in[4];
    const float* wqkv_w = (const float*)d_in[5];
    const float* wqkv_b = (const float*)d_in[6];
    const float* wo_w   = (const float*)d_in[7];
    const float* wo_b   = (const float*)d_in[8];
    const float* ln1_g  = (const float*)d_in[9];
    const float* ln1_b  = (const float*)d_in[10];
    const float* w1     = (const float*)d_in[11];
    const float* b1     = (const float*)d_in[12];
    const float* w2     = (const float*)d_in[13];
    const float* b2     = (const float*)d_in[14];
    float* outp = (float*)d_out;

    char* base = (char*)d_ws;
    const size_t SZ_X2    = (size_t)S_TOT * HID_ * 4;       // 14,155,776
    const size_t SZ_HPAIR = (size_t)S_TOT * HID_ * 2;       //  7,077,888 (one of pair)
    const size_t SZ_W1E   = (size_t)MLPP_ * HID_ * 2;       // 10,027,008 (one of pair)
    const size_t SZ_QKV   = (size_t)S_TOT * 3 * HID_ * 4;   // 42,467,328

    // [0, 14.2M): X2 (fp32)  — written L7, read L12. QKV aliases [0,42.5M) L3-L5.
    float*  x2      = (float*)(base + 0);
    float*  qkv     = (float*)(base + 0);
    // [14.2M, 28.3M): H2 pair (L8-L10); earlier WO pair (L6-L7); later W2 (L11-).
    ushort* h2_h    = (ushort*)(base + SZ_X2);
    ushort* h2_l    = h2_h + (size_t)S_TOT * HID_;
    ushort* woT_h   = (ushort*)(base + SZ_X2);
    ushort* woT_l   = woT_h + (size_t)HID_ * HID_;
    ushort* w2T_h   = (ushort*)(base + SZ_X2);               // [14.2M, 34.2M)
    ushort* w2T_l   = w2T_h + (size_t)HID_ * MLPP_;
    // [28.3M, 48.4M): W1 pair (L9-L10)
    ushort* w1T_h   = (ushort*)(base + SZ_X2 + 2 * SZ_HPAIR);
    ushort* w1T_l   = w1T_h + (size_t)MLPP_ * HID_;
    // [48.4M, 101.8M): MID pair (L10-L12)
    ushort* mid_h   = (ushort*)(base + SZ_X2 + 2 * SZ_HPAIR + 2 * SZ_W1E);
    ushort* mid_l   = mid_h + (size_t)S_TOT * MLPP_;
    // [42.5M, 56.6M): H pair (L2-L3), then AOUT pair (L5-L7)
    ushort* h_h     = (ushort*)(base + SZ_QKV);
    ushort* h_l     = h_h + (size_t)S_TOT * HID_;
    ushort* aout_h  = h_h;
    ushort* aout_l  = h_l;
    // [56.6M, 72.5M): wqkvT pair (L1-L3)
    ushort* wqkvT_h = (ushort*)(base + SZ_QKV + 2 * SZ_HPAIR);
    ushort* wqkvT_l = wqkvT_h + (size_t)3 * HID_ * HID_;

    // L1: wqkv convert+transpose
    convt_kernel<<<dim3(3456 / 32, 1152 / 32), 256, 0, stream>>>(
        wqkv_w, wqkvT_h, wqkvT_l, 1152, 3456, 1152);
    // L2: h = LN0(x)
    ln_bf_kernel<<<S_TOT / 4, 256, 0, stream>>>(x, ln0_g, ln0_b, h_h, h_l);
    // L3: qkv = h @ wqkv + b (fp32)
    gemm_bf16x3_kernel<0, false, false><<<dim3(3456 / 128, S_TOT / 128), 256, 0, stream>>>(
        h_h, h_l, wqkvT_h, wqkvT_l, wqkv_b, nullptr, qkv, nullptr, nullptr,
        S_TOT, 3456, 1152, 3456);
    // L4: RoPE
    rope_kernel<<<(S_TOT * 2 * NH_ * (HD_ / 2)) / 256, 256, 0, stream>>>(qkv, fc);
    // L5: attention -> aout pair
    attn_mfma_kernel<<<dim3(S_TOT / QBLK, NH_), 256, 0, stream>>>(qkv, offs, aout_h, aout_l);
    // L6: wo convert+transpose
    convt_kernel<<<dim3(1152 / 32, 1152 / 32), 256, 0, stream>>>(
        wo_w, woT_h, woT_l, 1152, 1152, 1152);
    // L7: x2 = x + aout @ wo + b
    gemm_bf16x3_kernel<0, true, false><<<dim3(HID_ / 128, S_TOT / 128), 256, 0, stream>>>(
        aout_h, aout_l, woT_h, woT_l, wo_b, x, x2, nullptr, nullptr,
        S_TOT, HID_, 1152, HID_);
    // L8: h2 = LN1(x2)
    ln_bf_kernel<<<S_TOT / 4, 256, 0, stream>>>(x2, ln1_g, ln1_b, h2_h, h2_l);
    // L9: w1 convert+transpose
    convt_kernel<<<dim3(MLPP_ / 32, 1152 / 32), 256, 0, stream>>>(
        w1, w1T_h, w1T_l, 1152, MLP_, 1152);
    // L10: mid = gelu(h2 @ w1 + b1), padded to 4352 with zeros
    gemm_bf16x3_kernel<1, false, true><<<dim3(MLPP_ / 128, S_TOT / 128), 256, 0, stream>>>(
        h2_h, h2_l, w1T_h, w1T_l, b1, nullptr, nullptr, mid_h, mid_l,
        S_TOT, MLP_, 1152, MLPP_);
    // L11: w2 convert+transpose
    convt_kernel<<<dim3(1152 / 32, MLPP_ / 32), 256, 0, stream>>>(
        w2, w2T_h, w2T_l, MLP_, 1152, MLPP_);
    // L12: out = x2 + mid @ w2 + b2
    gemm_bf16x3_kernel<0, true, false><<<dim3(HID_ / 128, S_TOT / 128), 256, 0, stream>>>(
        mid_h, mid_l, w2T_h, w2T_l, b2, x2, outp, nullptr, nullptr,
        S_TOT, HID_, MLPP_, HID_);
}

// Round 5
// 779.706 us; speedup vs baseline: 13.1233x; 1.1217x over previous
//
#include <hip/hip_runtime.h>
#include <hip/hip_bf16.h>
#include <cstddef>

// Problem constants
#define S_TOT 3072
#define HID_  1152
#define MLP_  4304
#define MLPP_ 4352   // MLP padded to multiple of 128 (pad is exact zeros)
#define NH_   16
#define HD_   72
#define SEGS_ 6
#define EPS_  1e-5f

typedef __attribute__((ext_vector_type(8))) short short8;
typedef __attribute__((ext_vector_type(4))) float floatx4;
typedef unsigned short ushort;
typedef unsigned int uint;

__device__ __forceinline__ ushort f2bf(float x)
{
    __hip_bfloat16 h = __float2bfloat16(x);
    return *reinterpret_cast<ushort*>(&h);
}
__device__ __forceinline__ float bf2f(ushort u)
{
    __hip_bfloat16 h = *reinterpret_cast<__hip_bfloat16*>(&u);
    return __bfloat162float(h);
}

__device__ __forceinline__ float gelu_tanh(float x)
{
    float x3 = x * x * x;
    return 0.5f * x * (1.0f + tanhf(0.7978845608028654f * (x + 0.044715f * x3)));
}

// ---------------------------------------------------------------------------
// LayerNorm -> split bf16 (hi, lo) output. One wave per row.
// ---------------------------------------------------------------------------
__global__ __launch_bounds__(256)
void ln_bf_kernel(const float* __restrict__ x, const float* __restrict__ g,
                  const float* __restrict__ b, ushort* __restrict__ yh,
                  ushort* __restrict__ yl)
{
    int row  = blockIdx.x * 4 + (threadIdx.x >> 6);
    int lane = threadIdx.x & 63;
    const float* xr = x + (size_t)row * HID_;
    float v[18];
    float s = 0.f;
#pragma unroll
    for (int i = 0; i < 18; ++i) { v[i] = xr[lane + i * 64]; s += v[i]; }
#pragma unroll
    for (int o = 32; o; o >>= 1) s += __shfl_xor(s, o);
    float mu = s * (1.0f / (float)HID_);
    float vs = 0.f;
#pragma unroll
    for (int i = 0; i < 18; ++i) { float d = v[i] - mu; vs += d * d; }
#pragma unroll
    for (int o = 32; o; o >>= 1) vs += __shfl_xor(vs, o);
    float rstd = rsqrtf(vs * (1.0f / (float)HID_) + EPS_);
#pragma unroll
    for (int i = 0; i < 18; ++i) {
        int c = lane + i * 64;
        float val = (v[i] - mu) * rstd * g[c] + b[c];
        ushort hi = f2bf(val);
        yh[(size_t)row * HID_ + c] = hi;
        yl[(size_t)row * HID_ + c] = f2bf(val - bf2f(hi));
    }
}

// ---------------------------------------------------------------------------
// Weight convert + transpose: in fp32 [Kin][Nin] -> out bf16 hi/lo [Nout][Kout]
// ---------------------------------------------------------------------------
__global__ __launch_bounds__(256)
void convt_kernel(const float* __restrict__ in, ushort* __restrict__ oh,
                  ushort* __restrict__ ol, int Kin, int Nin, int Kout)
{
    __shared__ float t[32][33];
    int n0 = blockIdx.x * 32, k0 = blockIdx.y * 32;
    int tx = threadIdx.x & 31, ty = threadIdx.x >> 5;  // ty 0..7
#pragma unroll
    for (int j = 0; j < 4; ++j) {
        int k = k0 + ty + 8 * j, n = n0 + tx;
        t[ty + 8 * j][tx] = (k < Kin && n < Nin) ? in[(size_t)k * Nin + n] : 0.f;
    }
    __syncthreads();
#pragma unroll
    for (int j = 0; j < 4; ++j) {
        int n = n0 + ty + 8 * j, k = k0 + tx;
        float v = t[tx][ty + 8 * j];
        ushort hi = f2bf(v);
        oh[(size_t)n * Kout + k] = hi;
        ol[(size_t)n * Kout + k] = f2bf(v - bf2f(hi));
    }
}

// ---------------------------------------------------------------------------
// Split-bf16 MFMA GEMM (unchanged from round 4)
// ---------------------------------------------------------------------------
__device__ __forceinline__ int swz(int row, int ke)
{
    return (row * 32 + ke) ^ ((row & 7) << 3);
}

template<int ACT, bool HAS_RES, bool OUT_PAIR>
__global__ __launch_bounds__(256)
void gemm_bf16x3_kernel(const ushort* __restrict__ Ah, const ushort* __restrict__ Al,
                        const ushort* __restrict__ Bh, const ushort* __restrict__ Bl,
                        const float* __restrict__ bias, const float* __restrict__ res,
                        float* __restrict__ C, ushort* __restrict__ Chi,
                        ushort* __restrict__ Clo, int M, int N, int K, int Ns)
{
    __shared__ ushort sAh[128 * 32], sAl[128 * 32], sBh[128 * 32], sBl[128 * 32];

    const int tid = threadIdx.x;
    const int bm = blockIdx.y * 128, bn = blockIdx.x * 128;
    const int lane = tid & 63, wv = tid >> 6;
    const int lm = lane & 15, lg = lane >> 4;
    const int wr = wv >> 1, wc = wv & 1;

    const int srow = tid >> 2, skb = (tid & 3) * 8;
    const size_t aoff0 = (size_t)(bm + srow) * K + skb;
    const size_t aoff1 = (size_t)(bm + srow + 64) * K + skb;
    const size_t boff0 = (size_t)(bn + srow) * K + skb;
    const size_t boff1 = (size_t)(bn + srow + 64) * K + skb;

    short8 rAh0, rAh1, rAl0, rAl1, rBh0, rBh1, rBl0, rBl1;
    auto LOAD = [&](int k0) {
        rAh0 = *reinterpret_cast<const short8*>(Ah + aoff0 + k0);
        rAh1 = *reinterpret_cast<const short8*>(Ah + aoff1 + k0);
        rAl0 = *reinterpret_cast<const short8*>(Al + aoff0 + k0);
        rAl1 = *reinterpret_cast<const short8*>(Al + aoff1 + k0);
        rBh0 = *reinterpret_cast<const short8*>(Bh + boff0 + k0);
        rBh1 = *reinterpret_cast<const short8*>(Bh + boff1 + k0);
        rBl0 = *reinterpret_cast<const short8*>(Bl + boff0 + k0);
        rBl1 = *reinterpret_cast<const short8*>(Bl + boff1 + k0);
    };

    floatx4 acc[4][4] = {};
    LOAD(0);

    const int w0 = swz(srow, skb), w1 = swz(srow + 64, skb);
    for (int k0 = 0; k0 < K; k0 += 32) {
        *reinterpret_cast<short8*>(&sAh[w0]) = rAh0;
        *reinterpret_cast<short8*>(&sAh[w1]) = rAh1;
        *reinterpret_cast<short8*>(&sAl[w0]) = rAl0;
        *reinterpret_cast<short8*>(&sAl[w1]) = rAl1;
        *reinterpret_cast<short8*>(&sBh[w0]) = rBh0;
        *reinterpret_cast<short8*>(&sBh[w1]) = rBh1;
        *reinterpret_cast<short8*>(&sBl[w0]) = rBl0;
        *reinterpret_cast<short8*>(&sBl[w1]) = rBl1;
        __syncthreads();
        if (k0 + 32 < K) LOAD(k0 + 32);

        short8 bhf[4], blf[4];
#pragma unroll
        for (int j = 0; j < 4; ++j) {
            int o = swz(wc * 64 + j * 16 + lm, 8 * lg);
            bhf[j] = *reinterpret_cast<const short8*>(&sBh[o]);
            blf[j] = *reinterpret_cast<const short8*>(&sBl[o]);
        }
#pragma unroll
        for (int i = 0; i < 4; ++i) {
            int o = swz(wr * 64 + i * 16 + lm, 8 * lg);
            short8 ahf = *reinterpret_cast<const short8*>(&sAh[o]);
            short8 alf = *reinterpret_cast<const short8*>(&sAl[o]);
#pragma unroll
            for (int j = 0; j < 4; ++j) {
                acc[i][j] = __builtin_amdgcn_mfma_f32_16x16x32_bf16(ahf, bhf[j], acc[i][j], 0, 0, 0);
                acc[i][j] = __builtin_amdgcn_mfma_f32_16x16x32_bf16(alf, bhf[j], acc[i][j], 0, 0, 0);
                acc[i][j] = __builtin_amdgcn_mfma_f32_16x16x32_bf16(ahf, blf[j], acc[i][j], 0, 0, 0);
            }
        }
        __syncthreads();
    }

#pragma unroll
    for (int i = 0; i < 4; ++i) {
#pragma unroll
        for (int j = 0; j < 4; ++j) {
#pragma unroll
            for (int r = 0; r < 4; ++r) {
                int m = bm + wr * 64 + i * 16 + lg * 4 + r;
                int n = bn + wc * 64 + j * 16 + lm;
                if (OUT_PAIR) {
                    float v = 0.f;
                    if (n < N) {
                        v = acc[i][j][r] + bias[n];
                        if (ACT == 1) v = gelu_tanh(v);
                    }
                    ushort hi = f2bf(v);
                    Chi[(size_t)m * Ns + n] = hi;
                    Clo[(size_t)m * Ns + n] = f2bf(v - bf2f(hi));
                } else if (n < N) {
                    float v = acc[i][j][r] + bias[n];
                    if (ACT == 1) v = gelu_tanh(v);
                    if (HAS_RES) v += res[(size_t)m * Ns + n];
                    C[(size_t)m * Ns + n] = v;
                }
            }
        }
    }
}

// ---------------------------------------------------------------------------
// QKV post-process: rope Q,K -> bf16 [NH][S][96] (cols 72..95 zero);
// V -> bf16 transposed [NH][80][S] (rows 72..79 zero).
// Block = (64-token tile, head). All global I/O coalesced; V transposed in LDS.
// ---------------------------------------------------------------------------
__global__ __launch_bounds__(256)
void qkv_post_kernel(const float* __restrict__ qkv, const float* __restrict__ fc,
                     ushort* __restrict__ qh, ushort* __restrict__ kh,
                     ushort* __restrict__ vt)
{
    const int t0 = blockIdx.x * 64, head = blockIdx.y, tid = threadIdx.x;
    // ---- Q, K: rope + pack ----
#pragma unroll
    for (int p = 0; p < 2; ++p) {
        ushort* dst = p ? kh : qh;
        for (int c = tid; c < 64 * 36; c += 256) {
            int t = c / 36, j = c % 36;
            size_t src = (size_t)(t0 + t) * (3 * HID_) + (size_t)p * HID_ + head * HD_ + 2 * j;
            float a = qkv[src], b = qkv[src + 1];
            float cs = fc[(size_t)(t0 + t) * HD_ + 2 * j];
            float sn = fc[(size_t)(t0 + t) * HD_ + 2 * j + 1];
            float o0 = a * cs - b * sn, o1 = a * sn + b * cs;
            uint u = (uint)f2bf(o0) | ((uint)f2bf(o1) << 16);
            *reinterpret_cast<uint*>(&dst[((size_t)head * S_TOT + t0 + t) * 96 + 2 * j]) = u;
        }
        for (int c = tid; c < 64 * 12; c += 256) {  // zero cols 72..95
            int t = c / 12, q = c % 12;
            *reinterpret_cast<uint*>(&dst[((size_t)head * S_TOT + t0 + t) * 96 + 72 + 2 * q]) = 0u;
        }
    }
    // ---- V: transpose via LDS ----
    __shared__ ushort vs[72][76];  // stride 76 -> spread banks on transposed writes
    for (int c = tid; c < 64 * 72; c += 256) {
        int t = c / 72, d = c % 72;
        vs[d][t] = f2bf(qkv[(size_t)(t0 + t) * (3 * HID_) + 2 * HID_ + head * HD_ + d]);
    }
    __syncthreads();
    for (int c = tid; c < 80 * 16; c += 256) {  // 8B chunks: 80 rows x 16 chunks
        int d = c / 16, ch = c % 16;
        uint lo = 0, hi = 0;
        if (d < HD_) {
            lo = (uint)vs[d][ch * 4]     | ((uint)vs[d][ch * 4 + 1] << 16);
            hi = (uint)vs[d][ch * 4 + 2] | ((uint)vs[d][ch * 4 + 3] << 16);
        }
        uint2 u; u.x = lo; u.y = hi;
        *reinterpret_cast<uint2*>(&vt[((size_t)head * 80 + d) * S_TOT + t0 + ch * 4]) = u;
    }
}

// ---------------------------------------------------------------------------
// Flash-style MFMA attention, bf16-native inputs.
//   qh/kh: [NH][S][96] bf16 (rope'd, zero-padded)   vt: [NH][80][S] bf16
// Block = (64-query tile, head), 4 waves; wave owns 16-row strip.
// Staging = pure short8 copies; Q frags loaded global->reg once.
// LDS strides: Ks 104, Vt 104 (uniform bank spread on b128), Pl 72. 38.25 KB.
// ---------------------------------------------------------------------------
#define QBLK 64
#define KVBLK 64
#define KSS 104
#define VTS2 104
#define PLS 72

__global__ __launch_bounds__(256)
void attn_mfma2_kernel(const ushort* __restrict__ qh, const ushort* __restrict__ kh,
                       const ushort* __restrict__ vt, const int* __restrict__ offs,
                       ushort* __restrict__ oh, ushort* __restrict__ ol)
{
    __shared__ alignas(16) ushort Ks[KVBLK * KSS];
    __shared__ alignas(16) ushort Vt[80 * VTS2];
    __shared__ alignas(16) ushort Pl[QBLK * PLS];

    const int qt   = blockIdx.x;
    const int head = blockIdx.y;
    const int tid  = threadIdx.x;
    const int lane = tid & 63;
    const int wv   = tid >> 6;
    const int lm   = lane & 15;
    const int lg   = lane >> 4;
    const int q0   = qt * QBLK;

    int ofv[SEGS_ + 1];
#pragma unroll
    for (int i = 0; i <= SEGS_; ++i) ofv[i] = offs[i];

    // Q fragments direct from global (reused all 48 tiles)
    short8 qf[3];
#pragma unroll
    for (int ks = 0; ks < 3; ++ks)
        qf[ks] = *reinterpret_cast<const short8*>(
            &qh[((size_t)head * S_TOT + q0 + wv * 16 + lm) * 96 + ks * 32 + 8 * lg]);

    int qsegr[4];
#pragma unroll
    for (int r = 0; r < 4; ++r) {
        int t = q0 + wv * 16 + lg * 4 + r;
        int sg = 0;
#pragma unroll
        for (int i = 1; i <= SEGS_; ++i) sg += (t >= ofv[i]);
        qsegr[r] = sg;
    }

    const float kscale = 0.11785113019775793f;  // 1/sqrt(72)

    floatx4 of[5] = {};
    float   m_r[4], l_r[4];
#pragma unroll
    for (int r = 0; r < 4; ++r) { m_r[r] = -1e30f; l_r[r] = 0.f; }

    for (int kt = 0; kt < S_TOT / KVBLK; ++kt) {
        const int kv0 = kt * KVBLK;
        // ---- stage K: 64 rows x 96 cols = 768 short8 chunks (3/thread) ----
#pragma unroll
        for (int k = 0; k < 3; ++k) {
            int c = tid + k * 256;
            int r = c / 12, off = (c % 12) * 8;
            *reinterpret_cast<short8*>(&Ks[r * KSS + off]) =
                *reinterpret_cast<const short8*>(&kh[((size_t)head * S_TOT + kv0 + r) * 96 + off]);
        }
        // ---- stage V: 80 rows x 64 t = 640 short8 chunks ----
#pragma unroll
        for (int k = 0; k < 3; ++k) {
            int c = tid + k * 256;
            if (c < 640) {
                int r = c / 8, off = (c % 8) * 8;
                *reinterpret_cast<short8*>(&Vt[r * VTS2 + off]) =
                    *reinterpret_cast<const short8*>(&vt[((size_t)head * 80 + r) * S_TOT + kv0 + off]);
            }
        }
        __syncthreads();

        // ---- S = Q K^T ----
        floatx4 sf[4];
#pragma unroll
        for (int ct = 0; ct < 4; ++ct) {
            floatx4 acc = {0.f, 0.f, 0.f, 0.f};
#pragma unroll
            for (int ks = 0; ks < 3; ++ks) {
                short8 kb = *reinterpret_cast<const short8*>(
                    &Ks[(ct * 16 + lm) * KSS + ks * 32 + 8 * lg]);
                acc = __builtin_amdgcn_mfma_f32_16x16x32_bf16(qf[ks], kb, acc, 0, 0, 0);
            }
            sf[ct] = acc;
        }

        // ---- scale + segment bias ----
#pragma unroll
        for (int ct = 0; ct < 4; ++ct) {
            int tcol = kv0 + ct * 16 + lm;
            int ksg = 0;
#pragma unroll
            for (int i = 1; i <= SEGS_; ++i) ksg += (tcol >= ofv[i]);
#pragma unroll
            for (int r = 0; r < 4; ++r)
                sf[ct][r] = sf[ct][r] * kscale + ((qsegr[r] == ksg) ? 1.0f : 0.0f);
        }

        // ---- online softmax (exact defer: skip rescale when max didn't grow) ----
        float rm[4];
        bool grow = false;
#pragma unroll
        for (int r = 0; r < 4; ++r) {
            float mx = fmaxf(fmaxf(sf[0][r], sf[1][r]), fmaxf(sf[2][r], sf[3][r]));
            mx = fmaxf(mx, __shfl_xor(mx, 1));
            mx = fmaxf(mx, __shfl_xor(mx, 2));
            mx = fmaxf(mx, __shfl_xor(mx, 4));
            mx = fmaxf(mx, __shfl_xor(mx, 8));
            rm[r] = mx;
            grow = grow || (mx > m_r[r]);
        }
        if (__any((int)grow)) {
#pragma unroll
            for (int r = 0; r < 4; ++r) {
                float mn = fmaxf(m_r[r], rm[r]);
                float s = __expf(m_r[r] - mn);
                m_r[r] = mn;
                l_r[r] *= s;
#pragma unroll
                for (int ct = 0; ct < 5; ++ct) of[ct][r] *= s;
            }
        }
        float rs[4];
#pragma unroll
        for (int r = 0; r < 4; ++r) rs[r] = 0.f;
#pragma unroll
        for (int ct = 0; ct < 4; ++ct)
#pragma unroll
            for (int r = 0; r < 4; ++r) {
                float p = __expf(sf[ct][r] - m_r[r]);
                sf[ct][r] = p;
                rs[r] += p;
            }
#pragma unroll
        for (int r = 0; r < 4; ++r) {
            float s = rs[r];
            s += __shfl_xor(s, 1);
            s += __shfl_xor(s, 2);
            s += __shfl_xor(s, 4);
            s += __shfl_xor(s, 8);
            l_r[r] += s;
        }

        // ---- P -> LDS (wave-private strip), re-fragment as A ----
#pragma unroll
        for (int ct = 0; ct < 4; ++ct)
#pragma unroll
            for (int r = 0; r < 4; ++r)
                Pl[(wv * 16 + lg * 4 + r) * PLS + ct * 16 + lm] = f2bf(sf[ct][r]);

        short8 pa0 = *reinterpret_cast<const short8*>(&Pl[(wv * 16 + lm) * PLS + 8 * lg]);
        short8 pa1 = *reinterpret_cast<const short8*>(&Pl[(wv * 16 + lm) * PLS + 32 + 8 * lg]);

        // ---- O += P @ V ----
#pragma unroll
        for (int ct = 0; ct < 5; ++ct) {
            short8 v0 = *reinterpret_cast<const short8*>(&Vt[(ct * 16 + lm) * VTS2 + 8 * lg]);
            short8 v1 = *reinterpret_cast<const short8*>(&Vt[(ct * 16 + lm) * VTS2 + 32 + 8 * lg]);
            of[ct] = __builtin_amdgcn_mfma_f32_16x16x32_bf16(pa0, v0, of[ct], 0, 0, 0);
            of[ct] = __builtin_amdgcn_mfma_f32_16x16x32_bf16(pa1, v1, of[ct], 0, 0, 0);
        }
        __syncthreads();
    }

    float inv[4];
#pragma unroll
    for (int r = 0; r < 4; ++r) inv[r] = 1.0f / l_r[r];
#pragma unroll
    for (int ct = 0; ct < 5; ++ct) {
        int d = ct * 16 + lm;
        if (d < HD_) {
#pragma unroll
            for (int r = 0; r < 4; ++r) {
                int row = q0 + wv * 16 + lg * 4 + r;
                float v = of[ct][r] * inv[r];
                ushort hi = f2bf(v);
                oh[(size_t)row * HID_ + head * HD_ + d] = hi;
                ol[(size_t)row * HID_ + head * HD_ + d] = f2bf(v - bf2f(hi));
            }
        }
    }
}

// ---------------------------------------------------------------------------
// Launch. Workspace: liveness-aliased, peak = 101.8 MB (unchanged).
// qh/kh/vt [56.6M, 83.4M) live only L4->L5 (over dead wqkvT + pre-MID region).
// ---------------------------------------------------------------------------
extern "C" void kernel_launch(void* const* d_in, const int* in_sizes, int n_in,
                              void* d_out, int out_size, void* d_ws, size_t ws_size,
                              hipStream_t stream)
{
    const float* x      = (const float*)d_in[0];
    const int*   offs   = (const int*)  d_in[1];
    const float* fc     = (const float*)d_in[2];
    const float* ln0_g  = (const float*)d_in[3];
    const float* ln0_b  = (const float*)d_in[4];
    const float* wqkv_w = (const float*)d_in[5];
    const float* wqkv_b = (const float*)d_in[6];
    const float* wo_w   = (const float*)d_in[7];
    const float* wo_b   = (const float*)d_in[8];
    const float* ln1_g  = (const float*)d_in[9];
    const float* ln1_b  = (const float*)d_in[10];
    const float* w1     = (const float*)d_in[11];
    const float* b1     = (const float*)d_in[12];
    const float* w2     = (const float*)d_in[13];
    const float* b2     = (const float*)d_in[14];
    float* outp = (float*)d_out;

    char* base = (char*)d_ws;
    const size_t SZ_X2    = (size_t)S_TOT * HID_ * 4;       // 14,155,776
    const size_t SZ_HPAIR = (size_t)S_TOT * HID_ * 2;       //  7,077,888
    const size_t SZ_W1E   = (size_t)MLPP_ * HID_ * 2;       // 10,027,008
    const size_t SZ_QKV   = (size_t)S_TOT * 3 * HID_ * 4;   // 42,467,328

    float*  x2      = (float*)(base + 0);
    float*  qkv     = (float*)(base + 0);
    ushort* h2_h    = (ushort*)(base + SZ_X2);
    ushort* h2_l    = h2_h + (size_t)S_TOT * HID_;
    ushort* woT_h   = (ushort*)(base + SZ_X2);
    ushort* woT_l   = woT_h + (size_t)HID_ * HID_;
    ushort* w2T_h   = (ushort*)(base + SZ_X2);
    ushort* w2T_l   = w2T_h + (size_t)HID_ * MLPP_;
    ushort* w1T_h   = (ushort*)(base + SZ_X2 + 2 * SZ_HPAIR);
    ushort* w1T_l   = w1T_h + (size_t)MLPP_ * HID_;
    ushort* mid_h   = (ushort*)(base + SZ_X2 + 2 * SZ_HPAIR + 2 * SZ_W1E);
    ushort* mid_l   = mid_h + (size_t)S_TOT * MLPP_;
    ushort* h_h     = (ushort*)(base + SZ_QKV);
    ushort* h_l     = h_h + (size_t)S_TOT * HID_;
    ushort* aout_h  = h_h;
    ushort* aout_l  = h_l;
    ushort* wqkvT_h = (ushort*)(base + SZ_QKV + 2 * SZ_HPAIR);
    ushort* wqkvT_l = wqkvT_h + (size_t)3 * HID_ * HID_;
    // attention bf16 layouts, live L4->L5 only (overlay dead wqkvT + pre-MID)
    ushort* qh      = (ushort*)(base + SZ_QKV + 2 * SZ_HPAIR);
    ushort* kh      = qh + (size_t)NH_ * S_TOT * 96;
    ushort* vt      = kh + (size_t)NH_ * S_TOT * 96;

    // L1: wqkv convert+transpose
    convt_kernel<<<dim3(3456 / 32, 1152 / 32), 256, 0, stream>>>(
        wqkv_w, wqkvT_h, wqkvT_l, 1152, 3456, 1152);
    // L2: h = LN0(x)
    ln_bf_kernel<<<S_TOT / 4, 256, 0, stream>>>(x, ln0_g, ln0_b, h_h, h_l);
    // L3: qkv = h @ wqkv + b (fp32)
    gemm_bf16x3_kernel<0, false, false><<<dim3(3456 / 128, S_TOT / 128), 256, 0, stream>>>(
        h_h, h_l, wqkvT_h, wqkvT_l, wqkv_b, nullptr, qkv, nullptr, nullptr,
        S_TOT, 3456, 1152, 3456);
    // L4: rope + bf16 pack + V transpose
    qkv_post_kernel<<<dim3(S_TOT / 64, NH_), 256, 0, stream>>>(qkv, fc, qh, kh, vt);
    // L5: attention -> aout pair
    attn_mfma2_kernel<<<dim3(S_TOT / QBLK, NH_), 256, 0, stream>>>(
        qh, kh, vt, offs, aout_h, aout_l);
    // L6: wo convert+transpose
    convt_kernel<<<dim3(1152 / 32, 1152 / 32), 256, 0, stream>>>(
        wo_w, woT_h, woT_l, 1152, 1152, 1152);
    // L7: x2 = x + aout @ wo + b
    gemm_bf16x3_kernel<0, true, false><<<dim3(HID_ / 128, S_TOT / 128), 256, 0, stream>>>(
        aout_h, aout_l, woT_h, woT_l, wo_b, x, x2, nullptr, nullptr,
        S_TOT, HID_, 1152, HID_);
    // L8: h2 = LN1(x2)
    ln_bf_kernel<<<S_TOT / 4, 256, 0, stream>>>(x2, ln1_g, ln1_b, h2_h, h2_l);
    // L9: w1 convert+transpose
    convt_kernel<<<dim3(MLPP_ / 32, 1152 / 32), 256, 0, stream>>>(
        w1, w1T_h, w1T_l, 1152, MLP_, 1152);
    // L10: mid = gelu(h2 @ w1 + b1)
    gemm_bf16x3_kernel<1, false, true><<<dim3(MLPP_ / 128, S_TOT / 128), 256, 0, stream>>>(
        h2_h, h2_l, w1T_h, w1T_l, b1, nullptr, nullptr, mid_h, mid_l,
        S_TOT, MLP_, 1152, MLPP_);
    // L11: w2 convert+transpose
    convt_kernel<<<dim3(1152 / 32, MLPP_ / 32), 256, 0, stream>>>(
        w2, w2T_h, w2T_l, MLP_, 1152, MLPP_);
    // L12: out = x2 + mid @ w2 + b2
    gemm_bf16x3_kernel<0, true, false><<<dim3(HID_ / 128, S_TOT / 128), 256, 0, stream>>>(
        mid_h, mid_l, w2T_h, w2T_l, b2, x2, outp, nullptr, nullptr,
        S_TOT, HID_, MLPP_, HID_);
}

// Round 7
// 635.606 us; speedup vs baseline: 16.0985x; 1.2267x over previous
//
#include <hip/hip_runtime.h>
#include <hip/hip_bf16.h>
#include <cstddef>

// Problem constants
#define S_TOT 3072
#define HID_  1152
#define MLP_  4304
#define MLPP_ 4352   // MLP padded to multiple of 128 (pad is exact zeros)
#define NH_   16
#define HD_   72
#define SEGS_ 6
#define EPS_  1e-5f

typedef __attribute__((ext_vector_type(8))) short short8;
typedef __attribute__((ext_vector_type(4))) float floatx4;
typedef unsigned short ushort;
typedef unsigned int uint;

__device__ __forceinline__ ushort f2bf(float x)
{
    __hip_bfloat16 h = __float2bfloat16(x);
    return *reinterpret_cast<ushort*>(&h);
}
__device__ __forceinline__ float bf2f(ushort u)
{
    __hip_bfloat16 h = *reinterpret_cast<__hip_bfloat16*>(&u);
    return __bfloat162float(h);
}

__device__ __forceinline__ float gelu_tanh(float x)
{
    float x3 = x * x * x;
    return 0.5f * x * (1.0f + tanhf(0.7978845608028654f * (x + 0.044715f * x3)));
}

__device__ __forceinline__ float bperm_f(int srclane, float v)
{
    return __int_as_float(__builtin_amdgcn_ds_bpermute(srclane * 4, __float_as_int(v)));
}

// ---------------------------------------------------------------------------
// LayerNorm -> split bf16 (hi, lo) output. One wave per row.
// ---------------------------------------------------------------------------
__global__ __launch_bounds__(256)
void ln_bf_kernel(const float* __restrict__ x, const float* __restrict__ g,
                  const float* __restrict__ b, ushort* __restrict__ yh,
                  ushort* __restrict__ yl)
{
    int row  = blockIdx.x * 4 + (threadIdx.x >> 6);
    int lane = threadIdx.x & 63;
    const float* xr = x + (size_t)row * HID_;
    float v[18];
    float s = 0.f;
#pragma unroll
    for (int i = 0; i < 18; ++i) { v[i] = xr[lane + i * 64]; s += v[i]; }
#pragma unroll
    for (int o = 32; o; o >>= 1) s += __shfl_xor(s, o);
    float mu = s * (1.0f / (float)HID_);
    float vs = 0.f;
#pragma unroll
    for (int i = 0; i < 18; ++i) { float d = v[i] - mu; vs += d * d; }
#pragma unroll
    for (int o = 32; o; o >>= 1) vs += __shfl_xor(vs, o);
    float rstd = rsqrtf(vs * (1.0f / (float)HID_) + EPS_);
#pragma unroll
    for (int i = 0; i < 18; ++i) {
        int c = lane + i * 64;
        float val = (v[i] - mu) * rstd * g[c] + b[c];
        ushort hi = f2bf(val);
        yh[(size_t)row * HID_ + c] = hi;
        yl[(size_t)row * HID_ + c] = f2bf(val - bf2f(hi));
    }
}

// ---------------------------------------------------------------------------
// Weight convert + transpose: fp32 [Kin][Nin] -> bf16 hi (and optional lo)
// [Nout][Kout] transposed, zero-padded.
// ---------------------------------------------------------------------------
__global__ __launch_bounds__(256)
void convt_kernel(const float* __restrict__ in, ushort* __restrict__ oh,
                  ushort* __restrict__ ol, int Kin, int Nin, int Kout)
{
    __shared__ float t[32][33];
    int n0 = blockIdx.x * 32, k0 = blockIdx.y * 32;
    int tx = threadIdx.x & 31, ty = threadIdx.x >> 5;  // ty 0..7
#pragma unroll
    for (int j = 0; j < 4; ++j) {
        int k = k0 + ty + 8 * j, n = n0 + tx;
        t[ty + 8 * j][tx] = (k < Kin && n < Nin) ? in[(size_t)k * Nin + n] : 0.f;
    }
    __syncthreads();
#pragma unroll
    for (int j = 0; j < 4; ++j) {
        int n = n0 + ty + 8 * j, k = k0 + tx;
        float v = t[tx][ty + 8 * j];
        ushort hi = f2bf(v);
        oh[(size_t)n * Kout + k] = hi;
        if (ol) ol[(size_t)n * Kout + k] = f2bf(v - bf2f(hi));
    }
}

// ---------------------------------------------------------------------------
// 2-term split-bf16 MFMA GEMM: C = act(A @ B^T + bias) (+res)
//   C ~= Ah Bh + Al Bh  (weight-lo dropped: contributes <~1e-3 abs)
// 128x128 tile, BK=32, 4 waves, 4x4 fragments, XOR-swizzled LDS (24 KB).
// ---------------------------------------------------------------------------
__device__ __forceinline__ int swz(int row, int ke)
{
    return (row * 32 + ke) ^ ((row & 7) << 3);
}

template<int ACT, bool HAS_RES, bool OUT_PAIR>
__global__ __launch_bounds__(256)
void gemm_bf16x2_kernel(const ushort* __restrict__ Ah, const ushort* __restrict__ Al,
                        const ushort* __restrict__ Bh,
                        const float* __restrict__ bias, const float* __restrict__ res,
                        float* __restrict__ C, ushort* __restrict__ Chi,
                        ushort* __restrict__ Clo, int M, int N, int K, int Ns)
{
    __shared__ ushort sAh[128 * 32], sAl[128 * 32], sBh[128 * 32];

    const int tid = threadIdx.x;
    const int bm = blockIdx.y * 128, bn = blockIdx.x * 128;
    const int lane = tid & 63, wv = tid >> 6;
    const int lm = lane & 15, lg = lane >> 4;
    const int wr = wv >> 1, wc = wv & 1;

    const int srow = tid >> 2, skb = (tid & 3) * 8;
    const size_t aoff0 = (size_t)(bm + srow) * K + skb;
    const size_t aoff1 = (size_t)(bm + srow + 64) * K + skb;
    const size_t boff0 = (size_t)(bn + srow) * K + skb;
    const size_t boff1 = (size_t)(bn + srow + 64) * K + skb;

    short8 rAh0, rAh1, rAl0, rAl1, rBh0, rBh1;
    auto LOAD = [&](int k0) {
        rAh0 = *reinterpret_cast<const short8*>(Ah + aoff0 + k0);
        rAh1 = *reinterpret_cast<const short8*>(Ah + aoff1 + k0);
        rAl0 = *reinterpret_cast<const short8*>(Al + aoff0 + k0);
        rAl1 = *reinterpret_cast<const short8*>(Al + aoff1 + k0);
        rBh0 = *reinterpret_cast<const short8*>(Bh + boff0 + k0);
        rBh1 = *reinterpret_cast<const short8*>(Bh + boff1 + k0);
    };

    floatx4 acc[4][4] = {};
    LOAD(0);

    const int w0 = swz(srow, skb), w1 = swz(srow + 64, skb);
    for (int k0 = 0; k0 < K; k0 += 32) {
        *reinterpret_cast<short8*>(&sAh[w0]) = rAh0;
        *reinterpret_cast<short8*>(&sAh[w1]) = rAh1;
        *reinterpret_cast<short8*>(&sAl[w0]) = rAl0;
        *reinterpret_cast<short8*>(&sAl[w1]) = rAl1;
        *reinterpret_cast<short8*>(&sBh[w0]) = rBh0;
        *reinterpret_cast<short8*>(&sBh[w1]) = rBh1;
        __syncthreads();
        if (k0 + 32 < K) LOAD(k0 + 32);

        short8 bhf[4];
#pragma unroll
        for (int j = 0; j < 4; ++j) {
            int o = swz(wc * 64 + j * 16 + lm, 8 * lg);
            bhf[j] = *reinterpret_cast<const short8*>(&sBh[o]);
        }
#pragma unroll
        for (int i = 0; i < 4; ++i) {
            int o = swz(wr * 64 + i * 16 + lm, 8 * lg);
            short8 ahf = *reinterpret_cast<const short8*>(&sAh[o]);
            short8 alf = *reinterpret_cast<const short8*>(&sAl[o]);
#pragma unroll
            for (int j = 0; j < 4; ++j) {
                acc[i][j] = __builtin_amdgcn_mfma_f32_16x16x32_bf16(ahf, bhf[j], acc[i][j], 0, 0, 0);
                acc[i][j] = __builtin_amdgcn_mfma_f32_16x16x32_bf16(alf, bhf[j], acc[i][j], 0, 0, 0);
            }
        }
        __syncthreads();
    }

#pragma unroll
    for (int i = 0; i < 4; ++i) {
#pragma unroll
        for (int j = 0; j < 4; ++j) {
#pragma unroll
            for (int r = 0; r < 4; ++r) {
                int m = bm + wr * 64 + i * 16 + lg * 4 + r;
                int n = bn + wc * 64 + j * 16 + lm;
                if (OUT_PAIR) {
                    float v = 0.f;
                    if (n < N) {
                        v = acc[i][j][r] + bias[n];
                        if (ACT == 1) v = gelu_tanh(v);
                    }
                    ushort hi = f2bf(v);
                    Chi[(size_t)m * Ns + n] = hi;
                    Clo[(size_t)m * Ns + n] = f2bf(v - bf2f(hi));
                } else if (n < N) {
                    float v = acc[i][j][r] + bias[n];
                    if (ACT == 1) v = gelu_tanh(v);
                    if (HAS_RES) v += res[(size_t)m * Ns + n];
                    C[(size_t)m * Ns + n] = v;
                }
            }
        }
    }
}

// ---------------------------------------------------------------------------
// QKV post-process: rope Q (pre-scaled by 1/sqrt(HD)), K -> bf16 [NH][S][96]
// (cols 72..95 zero); V -> bf16 transposed [NH][80][S] (rows 72..79 zero).
// ---------------------------------------------------------------------------
__global__ __launch_bounds__(256)
void qkv_post_kernel(const float* __restrict__ qkv, const float* __restrict__ fc,
                     ushort* __restrict__ qh, ushort* __restrict__ kh,
                     ushort* __restrict__ vt)
{
    const int t0 = blockIdx.x * 64, head = blockIdx.y, tid = threadIdx.x;
    const float kscale = 0.11785113019775793f;  // 1/sqrt(72), folded into Q
#pragma unroll
    for (int p = 0; p < 2; ++p) {
        ushort* dst = p ? kh : qh;
        float sc = p ? 1.0f : kscale;
        for (int c = tid; c < 64 * 36; c += 256) {
            int t = c / 36, j = c % 36;
            size_t src = (size_t)(t0 + t) * (3 * HID_) + (size_t)p * HID_ + head * HD_ + 2 * j;
            float a = qkv[src], b = qkv[src + 1];
            float cs = fc[(size_t)(t0 + t) * HD_ + 2 * j];
            float sn = fc[(size_t)(t0 + t) * HD_ + 2 * j + 1];
            float o0 = (a * cs - b * sn) * sc, o1 = (a * sn + b * cs) * sc;
            uint u = (uint)f2bf(o0) | ((uint)f2bf(o1) << 16);
            *reinterpret_cast<uint*>(&dst[((size_t)head * S_TOT + t0 + t) * 96 + 2 * j]) = u;
        }
        for (int c = tid; c < 64 * 12; c += 256) {
            int t = c / 12, q = c % 12;
            *reinterpret_cast<uint*>(&dst[((size_t)head * S_TOT + t0 + t) * 96 + 72 + 2 * q]) = 0u;
        }
    }
    __shared__ ushort vs[72][76];
    for (int c = tid; c < 64 * 72; c += 256) {
        int t = c / 72, d = c % 72;
        vs[d][t] = f2bf(qkv[(size_t)(t0 + t) * (3 * HID_) + 2 * HID_ + head * HD_ + d]);
    }
    __syncthreads();
    for (int c = tid; c < 80 * 16; c += 256) {
        int d = c / 16, ch = c % 16;
        uint lo = 0, hi = 0;
        if (d < HD_) {
            lo = (uint)vs[d][ch * 4]     | ((uint)vs[d][ch * 4 + 1] << 16);
            hi = (uint)vs[d][ch * 4 + 2] | ((uint)vs[d][ch * 4 + 3] << 16);
        }
        uint2 u; u.x = lo; u.y = hi;
        *reinterpret_cast<uint2*>(&vt[((size_t)head * 80 + d) * S_TOT + t0 + ch * 4]) = u;
    }
}

// ---------------------------------------------------------------------------
// Flash attention with SWAPPED QK^T (S^T = mfma(K,Q)): each lane owns ONE
// query row (q = lane&15); its 16 P-values per tile are lane-local, so
// max/sum are 15 in-lane ops + 2 shfl. Segment bias is folded into the exp
// constant when the key tile is segment-uniform (block-uniform branch).
// m,l are per-lane scalars; O-rescale scales redistributed by 4 ds_bpermute
// only when the running max grows (rare). P round-trip: 8 packed ds_write_b32.
// ---------------------------------------------------------------------------
#define QBLK 64
#define KVBLK 64
#define KSS 104
#define VTS2 104
#define PLS 72

__global__ __launch_bounds__(256)
void attn_mfma3_kernel(const ushort* __restrict__ qh, const ushort* __restrict__ kh,
                       const ushort* __restrict__ vt, const int* __restrict__ offs,
                       ushort* __restrict__ oh, ushort* __restrict__ ol)
{
    __shared__ alignas(16) ushort Ks[KVBLK * KSS];
    __shared__ alignas(16) ushort Vt[80 * VTS2];
    __shared__ alignas(16) ushort Pl[QBLK * PLS];

    const int qt   = blockIdx.x;
    const int head = blockIdx.y;
    const int tid  = threadIdx.x;
    const int lane = tid & 63;
    const int wv   = tid >> 6;
    const int lm   = lane & 15;
    const int lg   = lane >> 4;
    const int q0   = qt * QBLK;

    int ofv[SEGS_ + 1];
#pragma unroll
    for (int i = 0; i <= SEGS_; ++i) ofv[i] = offs[i];
    auto segof = [&](int t) {
        int s = 0;
#pragma unroll
        for (int i = 1; i <= SEGS_; ++i) s += (t >= ofv[i]);
        return s;
    };

    // Q fragments (pre-scaled by 1/sqrt(HD) at pack time); used as B operand
    short8 qf[3];
#pragma unroll
    for (int ks = 0; ks < 3; ++ks)
        qf[ks] = *reinterpret_cast<const short8*>(
            &qh[((size_t)head * S_TOT + q0 + wv * 16 + lm) * 96 + ks * 32 + 8 * lg]);

    const int qseg = segof(q0 + wv * 16 + lm);  // this lane's query segment

    floatx4 of[5] = {};
    float m_run = -1e30f, l_run = 0.f;

    for (int kt = 0; kt < S_TOT / KVBLK; ++kt) {
        const int kv0 = kt * KVBLK;
        // ---- stage K ----
#pragma unroll
        for (int k = 0; k < 3; ++k) {
            int c = tid + k * 256;
            int r = c / 12, off = (c % 12) * 8;
            *reinterpret_cast<short8*>(&Ks[r * KSS + off]) =
                *reinterpret_cast<const short8*>(&kh[((size_t)head * S_TOT + kv0 + r) * 96 + off]);
        }
        // ---- stage V ----
#pragma unroll
        for (int k = 0; k < 3; ++k) {
            int c = tid + k * 256;
            if (c < 640) {
                int r = c / 8, off = (c % 8) * 8;
                *reinterpret_cast<short8*>(&Vt[r * VTS2 + off]) =
                    *reinterpret_cast<const short8*>(&vt[((size_t)head * 80 + r) * S_TOT + kv0 + off]);
            }
        }
        __syncthreads();

        // ---- S^T = K Q^T : lane holds P[q=lm][key=16ct+4lg+r], scaled ----
        floatx4 sf[4];
#pragma unroll
        for (int ct = 0; ct < 4; ++ct) {
            floatx4 acc = {0.f, 0.f, 0.f, 0.f};
#pragma unroll
            for (int ks = 0; ks < 3; ++ks) {
                short8 kb = *reinterpret_cast<const short8*>(
                    &Ks[(ct * 16 + lm) * KSS + ks * 32 + 8 * lg]);
                acc = __builtin_amdgcn_mfma_f32_16x16x32_bf16(kb, qf[ks], acc, 0, 0, 0);
            }
            sf[ct] = acc;
        }

        // ---- segment bias (tile-uniform fast path, block-uniform branch) ----
        int ks0 = segof(kv0), ks1 = segof(kv0 + KVBLK - 1);
        float b = 0.f;
        if (ks0 == ks1) {
            b = (qseg == ks0) ? 1.0f : 0.0f;
        } else {
#pragma unroll
            for (int ct = 0; ct < 4; ++ct)
#pragma unroll
                for (int r = 0; r < 4; ++r) {
                    int ksg = segof(kv0 + 16 * ct + 4 * lg + r);
                    sf[ct][r] += (qseg == ksg) ? 1.0f : 0.0f;
                }
        }

        // ---- in-lane max over 16, reduce across the 4 sibling lanes ----
        float mx = fmaxf(fmaxf(fmaxf(sf[0][0], sf[0][1]), fmaxf(sf[0][2], sf[0][3])),
                         fmaxf(fmaxf(sf[1][0], sf[1][1]), fmaxf(sf[1][2], sf[1][3])));
        mx = fmaxf(mx, fmaxf(fmaxf(fmaxf(sf[2][0], sf[2][1]), fmaxf(sf[2][2], sf[2][3])),
                             fmaxf(fmaxf(sf[3][0], sf[3][1]), fmaxf(sf[3][2], sf[3][3]))));
        mx = fmaxf(mx, __shfl_xor(mx, 16));
        mx = fmaxf(mx, __shfl_xor(mx, 32));
        float mt = mx + b;

        if (__any((int)(mt > m_run))) {
            float mn = fmaxf(m_run, mt);
            float s = __expf(m_run - mn);   // == 1 for lanes whose max didn't grow
            m_run = mn;
            l_run *= s;
            float s_r[4];
#pragma unroll
            for (int r = 0; r < 4; ++r) s_r[r] = bperm_f(4 * lg + r, s);
#pragma unroll
            for (int ct = 0; ct < 5; ++ct)
#pragma unroll
                for (int r = 0; r < 4; ++r) of[ct][r] *= s_r[r];
        }

        // ---- p = exp(sf - (m - b)); in-lane sum; 2-shfl reduce ----
        float c = m_run - b;
        float sum = 0.f;
#pragma unroll
        for (int ct = 0; ct < 4; ++ct)
#pragma unroll
            for (int r = 0; r < 4; ++r) {
                float p = __expf(sf[ct][r] - c);
                sf[ct][r] = p;
                sum += p;
            }
        sum += __shfl_xor(sum, 16);
        sum += __shfl_xor(sum, 32);
        l_run += sum;

        // ---- P -> LDS (packed b32 writes, wave-private strip) ----
#pragma unroll
        for (int ct = 0; ct < 4; ++ct) {
            uint w0 = (uint)f2bf(sf[ct][0]) | ((uint)f2bf(sf[ct][1]) << 16);
            uint w1 = (uint)f2bf(sf[ct][2]) | ((uint)f2bf(sf[ct][3]) << 16);
            int e = (wv * 16 + lm) * PLS + 16 * ct + 4 * lg;
            *reinterpret_cast<uint*>(&Pl[e])     = w0;
            *reinterpret_cast<uint*>(&Pl[e + 2]) = w1;
        }

        short8 pa0 = *reinterpret_cast<const short8*>(&Pl[(wv * 16 + lm) * PLS + 8 * lg]);
        short8 pa1 = *reinterpret_cast<const short8*>(&Pl[(wv * 16 + lm) * PLS + 32 + 8 * lg]);

        // ---- O += P @ V ----
#pragma unroll
        for (int ct = 0; ct < 5; ++ct) {
            short8 v0 = *reinterpret_cast<const short8*>(&Vt[(ct * 16 + lm) * VTS2 + 8 * lg]);
            short8 v1 = *reinterpret_cast<const short8*>(&Vt[(ct * 16 + lm) * VTS2 + 32 + 8 * lg]);
            of[ct] = __builtin_amdgcn_mfma_f32_16x16x32_bf16(pa0, v0, of[ct], 0, 0, 0);
            of[ct] = __builtin_amdgcn_mfma_f32_16x16x32_bf16(pa1, v1, of[ct], 0, 0, 0);
        }
        __syncthreads();
    }

    // ---- epilogue: redistribute 1/l to row-indexed lanes, store hi/lo ----
    float invl = 1.0f / l_run;
    float inv_r[4];
#pragma unroll
    for (int r = 0; r < 4; ++r) inv_r[r] = bperm_f(4 * lg + r, invl);
#pragma unroll
    for (int ct = 0; ct < 5; ++ct) {
        int d = ct * 16 + lm;
        if (d < HD_) {
#pragma unroll
            for (int r = 0; r < 4; ++r) {
                int row = q0 + wv * 16 + lg * 4 + r;
                float v = of[ct][r] * inv_r[r];
                ushort hi = f2bf(v);
                oh[(size_t)row * HID_ + head * HD_ + d] = hi;
                ol[(size_t)row * HID_ + head * HD_ + d] = f2bf(v - bf2f(hi));
            }
        }
    }
}

// ---------------------------------------------------------------------------
// Launch. Workspace layout identical to round 5 (peak 101.8 MB, proven OK);
// weight-lo regions now simply unused.
// ---------------------------------------------------------------------------
extern "C" void kernel_launch(void* const* d_in, const int* in_sizes, int n_in,
                              void* d_out, int out_size, void* d_ws, size_t ws_size,
                              hipStream_t stream)
{
    const float* x      = (const float*)d_in[0];
    const int*   offs   = (const int*)  d_in[1];
    const float* fc     = (const float*)d_in[2];
    const float* ln0_g  = (const float*)d_in[3];
    const float* ln0_b  = (const float*)d_in[4];
    const float* wqkv_w = (const float*)d_in[5];
    const float* wqkv_b = (const float*)d_in[6];
    const float* wo_w   = (const float*)d_in[7];
    const float* wo_b   = (const float*)d_in[8];
    const float* ln1_g  = (const float*)d_in[9];
    const float* ln1_b  = (const float*)d_in[10];
    const float* w1     = (const float*)d_in[11];
    const float* b1     = (const float*)d_in[12];
    const float* w2     = (const float*)d_in[13];
    const float* b2     = (const float*)d_in[14];
    float* outp = (float*)d_out;

    char* base = (char*)d_ws;
    const size_t SZ_X2    = (size_t)S_TOT * HID_ * 4;
    const size_t SZ_HPAIR = (size_t)S_TOT * HID_ * 2;
    const size_t SZ_W1E   = (size_t)MLPP_ * HID_ * 2;
    const size_t SZ_QKV   = (size_t)S_TOT * 3 * HID_ * 4;

    float*  x2      = (float*)(base + 0);
    float*  qkv     = (float*)(base + 0);
    ushort* h2_h    = (ushort*)(base + SZ_X2);
    ushort* h2_l    = h2_h + (size_t)S_TOT * HID_;
    ushort* woT_h   = (ushort*)(base + SZ_X2);
    ushort* w2T_h   = (ushort*)(base + SZ_X2);
    ushort* w1T_h   = (ushort*)(base + SZ_X2 + 2 * SZ_HPAIR);
    ushort* mid_h   = (ushort*)(base + SZ_X2 + 2 * SZ_HPAIR + 2 * SZ_W1E);
    ushort* mid_l   = mid_h + (size_t)S_TOT * MLPP_;
    ushort* h_h     = (ushort*)(base + SZ_QKV);
    ushort* h_l     = h_h + (size_t)S_TOT * HID_;
    ushort* aout_h  = h_h;
    ushort* aout_l  = h_l;
    ushort* wqkvT_h = (ushort*)(base + SZ_QKV + 2 * SZ_HPAIR);
    // attention bf16 layouts, live L4->L5 only
    ushort* qh      = (ushort*)(base + SZ_QKV + 2 * SZ_HPAIR);
    ushort* kh      = qh + (size_t)NH_ * S_TOT * 96;
    ushort* vt      = kh + (size_t)NH_ * S_TOT * 96;
    // note: qh aliases wqkvT_h — wqkvT live L1-L3, qh live L4-L5: disjoint. OK.

    // L1: wqkv convert+transpose (hi only)
    convt_kernel<<<dim3(3456 / 32, 1152 / 32), 256, 0, stream>>>(
        wqkv_w, wqkvT_h, nullptr, 1152, 3456, 1152);
    // L2: h = LN0(x)
    ln_bf_kernel<<<S_TOT / 4, 256, 0, stream>>>(x, ln0_g, ln0_b, h_h, h_l);
    // L3: qkv = h @ wqkv + b (fp32)
    gemm_bf16x2_kernel<0, false, false><<<dim3(3456 / 128, S_TOT / 128), 256, 0, stream>>>(
        h_h, h_l, wqkvT_h, wqkv_b, nullptr, qkv, nullptr, nullptr,
        S_TOT, 3456, 1152, 3456);
    // L4: rope + bf16 pack (+1/sqrt(HD) folded into Q) + V transpose
    qkv_post_kernel<<<dim3(S_TOT / 64, NH_), 256, 0, stream>>>(qkv, fc, qh, kh, vt);
    // L5: attention -> aout pair
    attn_mfma3_kernel<<<dim3(S_TOT / QBLK, NH_), 256, 0, stream>>>(
        qh, kh, vt, offs, aout_h, aout_l);
    // L6: wo convert+transpose
    convt_kernel<<<dim3(1152 / 32, 1152 / 32), 256, 0, stream>>>(
        wo_w, woT_h, nullptr, 1152, 1152, 1152);
    // L7: x2 = x + aout @ wo + b
    gemm_bf16x2_kernel<0, true, false><<<dim3(HID_ / 128, S_TOT / 128), 256, 0, stream>>>(
        aout_h, aout_l, woT_h, wo_b, x, x2, nullptr, nullptr,
        S_TOT, HID_, 1152, HID_);
    // L8: h2 = LN1(x2)
    ln_bf_kernel<<<S_TOT / 4, 256, 0, stream>>>(x2, ln1_g, ln1_b, h2_h, h2_l);
    // L9: w1 convert+transpose
    convt_kernel<<<dim3(MLPP_ / 32, 1152 / 32), 256, 0, stream>>>(
        w1, w1T_h, nullptr, 1152, MLP_, 1152);
    // L10: mid = gelu(h2 @ w1 + b1)
    gemm_bf16x2_kernel<1, false, true><<<dim3(MLPP_ / 128, S_TOT / 128), 256, 0, stream>>>(
        h2_h, h2_l, w1T_h, b1, nullptr, nullptr, mid_h, mid_l,
        S_TOT, MLP_, 1152, MLPP_);
    // L11: w2 convert+transpose
    convt_kernel<<<dim3(1152 / 32, MLPP_ / 32), 256, 0, stream>>>(
        w2, w2T_h, nullptr, MLP_, 1152, MLPP_);
    // L12: out = x2 + mid @ w2 + b2
    gemm_bf16x2_kernel<0, true, false><<<dim3(HID_ / 128, S_TOT / 128), 256, 0, stream>>>(
        mid_h, mid_l, w2T_h, b2, x2, outp, nullptr, nullptr,
        S_TOT, HID_, MLPP_, HID_);
}